// Round 1
// 1395.444 us; speedup vs baseline: 1.0823x; 1.0823x over previous
//
#include <hip/hip_runtime.h>

typedef unsigned short u16;
typedef __attribute__((ext_vector_type(8))) short s8v;   // 8 x bf16 (4 VGPRs)
typedef __attribute__((ext_vector_type(4))) float f4v;   // MFMA acc

#define MFMA16(a, b, c) __builtin_amdgcn_mfma_f32_16x16x32_bf16(a, b, c, 0, 0, 0)

#define B_    2
#define L_    2048
#define D_    2048
#define H_    16
#define KVH_  4
#define HD_   128
#define F_    5632
#define FC_   1408        // F chunk (4 chunks)
#define MTOK  (B_ * L_)   // 4096
#define NEG_BIG (-1e30f)
#define SCL2E 0.127517416f   // 128^-0.5 * log2(e)

__device__ __forceinline__ float b2f(u16 h) {
  union { float f; unsigned u; } v; v.u = ((unsigned)h) << 16; return v.f;
}
__device__ __forceinline__ u16 f2b(float f) {
  union { float f; unsigned u; } v; v.f = f;
  unsigned r = v.u + 0x7FFFu + ((v.u >> 16) & 1u);
  return (u16)(r >> 16);
}
__device__ __forceinline__ s8v ld8(const u16* p) { return *reinterpret_cast<const s8v*>(p); }
__device__ __forceinline__ void st8(u16* p, s8v v) { *reinterpret_cast<s8v*>(p) = v; }
// async global->LDS, 16B per lane; lds dest = wave-uniform base + lane*16 [m97]
__device__ __forceinline__ void gld16(const u16* g, u16* l) {
  __builtin_amdgcn_global_load_lds((const __attribute__((address_space(1))) void*)g,
                                   (__attribute__((address_space(3))) void*)l, 16, 0, 0);
}

// ---------------- fp32 -> bf16 weight convert (grid-stride, 8/thread) -----
__global__ __launch_bounds__(256) void conv_k(const float* __restrict__ src,
                                              u16* __restrict__ dst, int n8) {
  int i = blockIdx.x * 256 + threadIdx.x;
  const int stride = gridDim.x * 256;
  for (; i < n8; i += stride) {
    const float* p = src + (size_t)i * 8;
    float4 a = *(const float4*)p, b = *(const float4*)(p + 4);
    float f[8] = {a.x, a.y, a.z, a.w, b.x, b.y, b.z, b.w};
    s8v o;
#pragma unroll
    for (int j = 0; j < 8; ++j) o[j] = (short)f2b(f[j]);
    st8(dst + (size_t)i * 8, o);
  }
}

// ---------------- RMSNorm: fp32 in -> bf16 out, one block per row ---------
__global__ __launch_bounds__(256) void rmsnorm_k(const float* __restrict__ x,
                                                 const float* __restrict__ w,
                                                 u16* __restrict__ out) {
  const int row = blockIdx.x, t = threadIdx.x;
  const float* xr = x + (size_t)row * D_ + t * 8;
  float4 a = *(const float4*)(xr);
  float4 b = *(const float4*)(xr + 4);
  float f[8] = {a.x, a.y, a.z, a.w, b.x, b.y, b.z, b.w};
  float ss = 0.f;
#pragma unroll
  for (int j = 0; j < 8; ++j) ss += f[j] * f[j];
#pragma unroll
  for (int m = 1; m < 64; m <<= 1) ss += __shfl_xor(ss, m);
  __shared__ float red[4];
  if ((t & 63) == 0) red[t >> 6] = ss;
  __syncthreads();
  float tot = red[0] + red[1] + red[2] + red[3];
  float inv = rsqrtf(tot * (1.f / D_) + 1e-6f);
  float4 wa = *(const float4*)(w + t * 8);
  float4 wb = *(const float4*)(w + t * 8 + 4);
  float wf[8] = {wa.x, wa.y, wa.z, wa.w, wb.x, wb.y, wb.z, wb.w};
  s8v o;
#pragma unroll
  for (int j = 0; j < 8; ++j) o[j] = (short)f2b(f[j] * inv * wf[j]);
  st8(out + (size_t)row * D_ + t * 8, o);
}

// ======== GEMM variant 1: A bf16, W bf16, global_load_lds staging =========
// C[M,N] = A[M,:K] * W[N,:K]^T ; m97-style 2-barrier K-loop.
template <bool C_F32>
__global__ __launch_bounds__(256) void gemm_bb(const u16* __restrict__ A, int lda,
                                               const u16* __restrict__ W, int ldw,
                                               const float* __restrict__ bias,
                                               const float* resid,
                                               const u16* gatein,
                                               void* Cv,
                                               int M, int N, int K) {
  __shared__ __align__(16) u16 As[128 * 32];
  __shared__ __align__(16) u16 Bs[128 * 32];
  const int t = threadIdx.x;
  const int l = t & 63, w = t >> 6;
  const int lr = l & 15, lg = l >> 4;
  const int m0 = blockIdx.y * 128, n0 = blockIdx.x * 128;
  const int wm = (w >> 1) * 64, wn = (w & 1) * 64;
  const int sr = t >> 2, sc = (t & 3) * 8;
  const u16* Ag0 = A + (size_t)(m0 + sr) * lda + sc;
  const u16* Ag1 = A + (size_t)(m0 + sr + 64) * lda + sc;
  const u16* Wg0 = W + (size_t)(n0 + sr) * ldw + sc;
  const u16* Wg1 = W + (size_t)(n0 + sr + 64) * ldw + sc;
  // wave-uniform LDS bases: thread t's 16B slot is at linear offset t*8 u16
  u16* As0 = &As[w * 512]; u16* As1 = &As[2048 + w * 512];
  u16* Bs0 = &Bs[w * 512]; u16* Bs1 = &Bs[2048 + w * 512];

  const f4v zero4 = {0.f, 0.f, 0.f, 0.f};
  f4v acc[4][4];
#pragma unroll
  for (int i = 0; i < 4; ++i)
#pragma unroll
    for (int j = 0; j < 4; ++j) acc[i][j] = zero4;

  for (int k0 = 0; k0 < K; k0 += 32) {
    __syncthreads();                       // prev iter's ds_reads done
    gld16(Ag0 + k0, As0);
    gld16(Ag1 + k0, As1);
    gld16(Wg0 + k0, Bs0);
    gld16(Wg1 + k0, Bs1);
    __syncthreads();                       // drains vmcnt -> LDS valid
    s8v af[4], bf[4];
#pragma unroll
    for (int i = 0; i < 4; ++i) {
      af[i] = ld8(&As[(wm + i * 16 + lr) * 32 + lg * 8]);
      bf[i] = ld8(&Bs[(wn + i * 16 + lr) * 32 + lg * 8]);
    }
#pragma unroll
    for (int i = 0; i < 4; ++i)
#pragma unroll
      for (int j = 0; j < 4; ++j)
        acc[i][j] = MFMA16(af[i], bf[j], acc[i][j]);
  }
  // epilogue: C/D layout col = lane&15, row = (lane>>4)*4 + reg  [m89]
#pragma unroll
  for (int j = 0; j < 4; ++j) {
    const int col = n0 + wn + j * 16 + lr;
    const float bv = bias ? bias[col] : 0.f;
#pragma unroll
    for (int i = 0; i < 4; ++i) {
      const int row = m0 + wm + i * 16 + lg * 4;
#pragma unroll
      for (int r = 0; r < 4; ++r) {
        float vv = acc[i][j][r] + bv;
        size_t off = (size_t)(row + r) * N + col;
        if (gatein) {
          float gf = b2f(gatein[off]);
          vv *= gf / (1.f + __expf(-gf));   // silu(gate) * up
        }
        if (resid) vv += resid[off];
        if (C_F32) ((float*)Cv)[off] = vv;
        else       ((u16*)Cv)[off]   = f2b(vv);
      }
    }
  }
}

// ======== GEMM variant 2 (fallback): A bf16, W fp32 staged in regs ========
template <bool C_F32>
__global__ __launch_bounds__(256) void gemm_nt(const u16* __restrict__ A, int lda,
                                               const float* __restrict__ W, int ldw,
                                               const float* __restrict__ bias,
                                               const float* resid,
                                               const u16* gatein,
                                               void* Cv,
                                               int M, int N, int K) {
  __shared__ __align__(16) u16 As[128 * 32];
  __shared__ __align__(16) u16 Bs[128 * 32];
  const int t = threadIdx.x;
  const int l = t & 63, w = t >> 6;
  const int lr = l & 15, lg = l >> 4;
  const int m0 = blockIdx.y * 128, n0 = blockIdx.x * 128;
  const int wm = (w >> 1) * 64, wn = (w & 1) * 64;
  const int sr = t >> 2, sc = (t & 3) * 8;
  const u16* Ag0 = A + (size_t)(m0 + sr) * lda + sc;
  const u16* Ag1 = A + (size_t)(m0 + sr + 64) * lda + sc;
  const float* Wg0 = W + (size_t)(n0 + sr) * ldw + sc;
  const float* Wg1 = W + (size_t)(n0 + sr + 64) * ldw + sc;

  const f4v zero4 = {0.f, 0.f, 0.f, 0.f};
  f4v acc[4][4];
#pragma unroll
  for (int i = 0; i < 4; ++i)
#pragma unroll
    for (int j = 0; j < 4; ++j) acc[i][j] = zero4;

  for (int k0 = 0; k0 < K; k0 += 32) {
    s8v a0 = ld8(Ag0 + k0), a1 = ld8(Ag1 + k0);
    float4 w0a = *(const float4*)(Wg0 + k0), w0b = *(const float4*)(Wg0 + k0 + 4);
    float4 w1a = *(const float4*)(Wg1 + k0), w1b = *(const float4*)(Wg1 + k0 + 4);
    float wf0[8] = {w0a.x, w0a.y, w0a.z, w0a.w, w0b.x, w0b.y, w0b.z, w0b.w};
    float wf1[8] = {w1a.x, w1a.y, w1a.z, w1a.w, w1b.x, w1b.y, w1b.z, w1b.w};
    s8v b0, b1;
#pragma unroll
    for (int j = 0; j < 8; ++j) { b0[j] = (short)f2b(wf0[j]); b1[j] = (short)f2b(wf1[j]); }
    __syncthreads();
    st8(&As[sr * 32 + sc], a0);
    st8(&As[(sr + 64) * 32 + sc], a1);
    st8(&Bs[sr * 32 + sc], b0);
    st8(&Bs[(sr + 64) * 32 + sc], b1);
    __syncthreads();
    s8v af[4], bf[4];
#pragma unroll
    for (int i = 0; i < 4; ++i) {
      af[i] = ld8(&As[(wm + i * 16 + lr) * 32 + lg * 8]);
      bf[i] = ld8(&Bs[(wn + i * 16 + lr) * 32 + lg * 8]);
    }
#pragma unroll
    for (int i = 0; i < 4; ++i)
#pragma unroll
      for (int j = 0; j < 4; ++j)
        acc[i][j] = MFMA16(af[i], bf[j], acc[i][j]);
  }
#pragma unroll
  for (int j = 0; j < 4; ++j) {
    const int col = n0 + wn + j * 16 + lr;
    const float bv = bias ? bias[col] : 0.f;
#pragma unroll
    for (int i = 0; i < 4; ++i) {
      const int row = m0 + wm + i * 16 + lg * 4;
#pragma unroll
      for (int r = 0; r < 4; ++r) {
        float vv = acc[i][j][r] + bv;
        size_t off = (size_t)(row + r) * N + col;
        if (gatein) {
          float gf = b2f(gatein[off]);
          vv *= gf / (1.f + __expf(-gf));
        }
        if (resid) vv += resid[off];
        if (C_F32) ((float*)Cv)[off] = vv;
        else       ((u16*)Cv)[off]   = f2b(vv);
      }
    }
  }
}

// ---------------- V transpose: bf16 [B,L,512] -> VT [B][KVH][HD][L] -------
__global__ __launch_bounds__(256) void transpose_v(const u16* __restrict__ V,
                                                   u16* __restrict__ VT) {
  __shared__ u16 tile[64][72];
  const int t = threadIdx.x;
  const int tok0 = blockIdx.x * 64;
  const int hd0 = blockIdx.y * 64;
  const int bk = blockIdx.z;           // b*KVH + kvh
  const int b = bk >> 2, kvh = bk & 3;
#pragma unroll
  for (int c = 0; c < 16; ++c) {
    int idx = t + c * 256;
    int tok = idx >> 6, hd = idx & 63;
    tile[tok][hd] = V[(size_t)(b * L_ + tok0 + tok) * 512 + kvh * 128 + hd0 + hd];
  }
  __syncthreads();
#pragma unroll
  for (int c = 0; c < 16; ++c) {
    int idx = t + c * 256;
    int tok = idx & 63, hd = idx >> 6;
    VT[(size_t)(bk * 128 + hd0 + hd) * L_ + tok0 + tok] = tile[tok][hd];
  }
}

// ---------------- Flash attention, causal, GQA (kv = h % 4), all bf16 -----
// q-tile 64, 4 waves (wave w owns q rows w*16..+15), k-tiles of 64 keys.
// v2: double-buffered global_load_lds staging (2-phase pipeline, T3/T14),
//     XOR-swizzled K/V tiles (linear dest + pre-swizzled source, rule 21),
//     reversed q-tile launch order (long causal blocks first), setprio (T5).
__global__ __launch_bounds__(256) void attn_k(const u16* __restrict__ Q,
                                              const u16* __restrict__ Kx,
                                              const u16* __restrict__ VT,
                                              u16* __restrict__ O) {
  __shared__ __align__(16) u16 KtB[2][64 * 128];   // [key][hd], swizzled
  __shared__ __align__(16) u16 VtB[2][128 * 64];   // [hd][key], swizzled
  __shared__ __align__(16) u16 Pb[4 * 16 * 72];    // per-wave [qlocal][key]
  const int t = threadIdx.x, l = t & 63, w = t >> 6;
  const int lr = l & 15, lg = l >> 4;
  const int bh = blockIdx.y, b = bh >> 4, h = bh & 15, kvh = h & 3;
  const int qt = (int)gridDim.x - 1 - blockIdx.x;  // heavy blocks dispatch first
  const int q0 = qt * 64;
  const int ktmax = qt;
  const f4v zero4 = {0.f, 0.f, 0.f, 0.f};

  // staging geometry: linear LDS dest (idx = c*256+t, 16B chunks);
  // source column pre-XOR'd so a swizzled read is conflict-free.
  const int kxr = t >> 4;                     // K: row-in-group 0..15
  const int kxc = (t & 15) ^ (kxr & 7);       // K: swizzled 16B chunk 0..15
  const int vxr = t >> 3;                     // V: row-in-group 0..31
  const int vxc = (t & 7) ^ (vxr & 7);        // V: swizzled 16B chunk 0..7
  const u16* Kg = Kx + (size_t)(b * L_) * 512 + kvh * 128;
  const u16* Vg = VT + (size_t)((b * 4 + kvh) * 128) * L_;

  auto stage = [&](int ktile, int bufi) {
#pragma unroll
    for (int c = 0; c < 4; ++c)
      gld16(Kg + (size_t)(ktile * 64 + c * 16 + kxr) * 512 + kxc * 8,
            &KtB[bufi][c * 2048 + w * 512]);
#pragma unroll
    for (int c = 0; c < 4; ++c)
      gld16(Vg + (size_t)(c * 32 + vxr) * L_ + ktile * 64 + vxc * 8,
            &VtB[bufi][c * 2048 + w * 512]);
  };

  // Q fragments (A-layout: m = lane&15, k = (lane>>4)*8+j)
  s8v qf[4];
#pragma unroll
  for (int kf = 0; kf < 4; ++kf)
    qf[kf] = ld8(Q + (size_t)(b * L_ + q0 + w * 16 + lr) * 2048 +
                 h * 128 + kf * 32 + lg * 8);

  float mrow[4], srow[4];
  f4v oacc[8];
#pragma unroll
  for (int r = 0; r < 4; ++r) { mrow[r] = NEG_BIG; srow[r] = 0.f; }
#pragma unroll
  for (int n = 0; n < 8; ++n) oacc[n] = zero4;
  u16* Pw = Pb + w * 16 * 72;

  int cur = 0;
  stage(0, 0);
  asm volatile("s_waitcnt vmcnt(0)" ::: "memory");
  __syncthreads();

  for (int kt = 0; kt <= ktmax; ++kt) {
    if (kt < ktmax) stage(kt + 1, cur ^ 1);   // async prefetch next tile

    // S = Q K^T  (1 mf x 4 nf, K=128 via 4 kf)
    f4v s[4];
#pragma unroll
    for (int nf = 0; nf < 4; ++nf) s[nf] = zero4;
    __builtin_amdgcn_s_setprio(1);
#pragma unroll
    for (int nf = 0; nf < 4; ++nf)
#pragma unroll
      for (int kf = 0; kf < 4; ++kf) {
        s8v bfr = ld8(&KtB[cur][(nf * 16 + lr) * 128 +
                                ((kf * 4 + lg) ^ (lr & 7)) * 8]);
        s[nf] = MFMA16(qf[kf], bfr, s[nf]);
      }
    __builtin_amdgcn_s_setprio(0);

    const bool needmask = (kt == ktmax);
#pragma unroll
    for (int nf = 0; nf < 4; ++nf)
#pragma unroll
      for (int r = 0; r < 4; ++r) {
        float vv = s[nf][r] * SCL2E;
        if (needmask) {
          int key = kt * 64 + nf * 16 + lr;
          int qr = q0 + w * 16 + lg * 4 + r;
          if (key > qr) vv = NEG_BIG;
        }
        s[nf][r] = vv;
      }

    // row max (16 lr-lanes x 4 nf)
    float tm[4];
#pragma unroll
    for (int r = 0; r < 4; ++r) {
      float m = fmaxf(fmaxf(s[0][r], s[1][r]), fmaxf(s[2][r], s[3][r]));
#pragma unroll
      for (int msk = 1; msk < 16; msk <<= 1) m = fmaxf(m, __shfl_xor(m, msk));
      tm[r] = m;
    }
    float al[4], rs[4];
#pragma unroll
    for (int r = 0; r < 4; ++r) {
      float mn = fmaxf(mrow[r], tm[r]);
      al[r] = exp2f(mrow[r] - mn);
      mrow[r] = mn;
      rs[r] = 0.f;
    }
    // P = exp2(S - m); bf16 P to per-wave LDS (wave-private, in-order DS)
#pragma unroll
    for (int nf = 0; nf < 4; ++nf)
#pragma unroll
      for (int r = 0; r < 4; ++r) {
        float p = exp2f(s[nf][r] - mrow[r]);
        rs[r] += p;
        Pw[(lg * 4 + r) * 72 + nf * 16 + lr] = f2b(p);
      }
#pragma unroll
    for (int r = 0; r < 4; ++r) {
#pragma unroll
      for (int msk = 1; msk < 16; msk <<= 1) rs[r] += __shfl_xor(rs[r], msk);
      srow[r] = srow[r] * al[r] + rs[r];
    }
#pragma unroll
    for (int n = 0; n < 8; ++n)
#pragma unroll
      for (int r = 0; r < 4; ++r) oacc[n][r] *= al[r];

    // O += P V
    s8v pa[2];
#pragma unroll
    for (int k2 = 0; k2 < 2; ++k2)
      pa[k2] = ld8(&Pw[lr * 72 + k2 * 32 + lg * 8]);
    __builtin_amdgcn_s_setprio(1);
#pragma unroll
    for (int n = 0; n < 8; ++n)
#pragma unroll
      for (int k2 = 0; k2 < 2; ++k2) {
        s8v vb = ld8(&VtB[cur][(n * 16 + lr) * 64 +
                               ((k2 * 4 + lg) ^ (lr & 7)) * 8]);
        oacc[n] = MFMA16(pa[k2], vb, oacc[n]);
      }
    __builtin_amdgcn_s_setprio(0);

    asm volatile("s_waitcnt vmcnt(0)" ::: "memory");  // prefetch landed
    __syncthreads();                                   // all waves done w/ cur
    cur ^= 1;
  }

  // normalize + store (bf16)
#pragma unroll
  for (int r = 0; r < 4; ++r) {
    float inv = 1.f / srow[r];
#pragma unroll
    for (int n = 0; n < 8; ++n) {
      size_t off = (size_t)(b * L_ + q0 + w * 16 + lg * 4 + r) * 2048 +
                   h * 128 + n * 16 + lr;
      O[off] = f2b(oacc[n][r] * inv);
    }
  }
}

// ---------------- launch ---------------------------------------------------
extern "C" void kernel_launch(void* const* d_in, const int* in_sizes, int n_in,
                              void* d_out, int out_size, void* d_ws, size_t ws_size,
                              hipStream_t stream) {
  const float* x    = (const float*)d_in[0];
  const float* ln1w = (const float*)d_in[1];
  const float* qw   = (const float*)d_in[2];
  const float* qb   = (const float*)d_in[3];
  const float* kw   = (const float*)d_in[4];
  const float* kb   = (const float*)d_in[5];
  const float* vw   = (const float*)d_in[6];
  const float* vbi  = (const float*)d_in[7];
  const float* ow   = (const float*)d_in[8];
  const float* ln2w = (const float*)d_in[9];
  const float* gw   = (const float*)d_in[10];
  const float* uw   = (const float*)d_in[11];
  const float* dw   = (const float*)d_in[12];
  float* out = (float*)d_out;

  char* ws = (char*)d_ws;
  u16* h    = (u16*)(ws);                  // 16 MiB
  u16* kbuf = (u16*)(ws + (16ull << 20));  // 4 MiB
  u16* vbuf = (u16*)(ws + (20ull << 20));  // 4 MiB
  u16* vt   = (u16*)(ws + (24ull << 20));  // 4 MiB
  u16* g    = (u16*)(ws + (16ull << 20));  // 11 MiB (phase C, reuses kb/vb)
  u16* qscr = (u16*)d_out;                 // bf16 Q scratch in d_out (16 MiB)

  dim3 blk(256);
  const bool big = ws_size >= 119537664ull;   // bf16-weight path needs ~114 MiB

  rmsnorm_k<<<MTOK, blk, 0, stream>>>(x, ln1w, h);

  if (big) {
    // bf16 weight pool at +28 MiB
    u16* wp = (u16*)(ws + (28ull << 20));
    u16* wq = wp;                          // 4,194,304 elems
    u16* wk = wq + 4194304;                // 1,048,576
    u16* wv = wk + 1048576;                // 1,048,576
    u16* wo = wv + 1048576;                // 4,194,304
    u16* wg = wo + 4194304;                // 11,534,336
    u16* wu = wg + 11534336;               // 11,534,336
    u16* wd = wu + 11534336;               // 11,534,336
    conv_k<<<2048, blk, 0, stream>>>(qw, wq, 4194304 / 8);
    conv_k<<<512, blk, 0, stream>>>(kw, wk, 1048576 / 8);
    conv_k<<<512, blk, 0, stream>>>(vw, wv, 1048576 / 8);
    conv_k<<<2048, blk, 0, stream>>>(ow, wo, 4194304 / 8);
    conv_k<<<2048, blk, 0, stream>>>(gw, wg, 11534336 / 8);
    conv_k<<<2048, blk, 0, stream>>>(uw, wu, 11534336 / 8);
    conv_k<<<2048, blk, 0, stream>>>(dw, wd, 11534336 / 8);

    gemm_bb<false><<<dim3(16, 32), blk, 0, stream>>>(h, D_, wq, D_, qb, nullptr, nullptr,
                                                     qscr, MTOK, 2048, 2048);
    gemm_bb<false><<<dim3(4, 32), blk, 0, stream>>>(h, D_, wk, D_, kb, nullptr, nullptr,
                                                    kbuf, MTOK, 512, 2048);
    gemm_bb<false><<<dim3(4, 32), blk, 0, stream>>>(h, D_, wv, D_, vbi, nullptr, nullptr,
                                                    vbuf, MTOK, 512, 2048);
    transpose_v<<<dim3(32, 2, 8), blk, 0, stream>>>(vbuf, vt);
    attn_k<<<dim3(32, 32), blk, 0, stream>>>(qscr, kbuf, vt, h);
    gemm_bb<true><<<dim3(16, 32), blk, 0, stream>>>(h, D_, wo, D_, nullptr, x, nullptr,
                                                    d_out, MTOK, 2048, 2048);
    rmsnorm_k<<<MTOK, blk, 0, stream>>>(out, ln2w, h);
    for (int fc = 0; fc < 4; ++fc) {
      const u16* gwc = wg + (size_t)fc * FC_ * D_;
      const u16* uwc = wu + (size_t)fc * FC_ * D_;
      const u16* dwc = wd + (size_t)fc * FC_;
      gemm_bb<false><<<dim3(11, 32), blk, 0, stream>>>(h, D_, gwc, D_, nullptr, nullptr,
                                                       nullptr, g, MTOK, FC_, 2048);
      gemm_bb<false><<<dim3(11, 32), blk, 0, stream>>>(h, D_, uwc, D_, nullptr, nullptr,
                                                       g, g, MTOK, FC_, 2048);
      gemm_bb<true><<<dim3(16, 32), blk, 0, stream>>>(g, FC_, dwc, F_, nullptr, out,
                                                      nullptr, d_out, MTOK, 2048, FC_);
    }
  } else {
    // fallback: fp32-weight register staging (round-4 proven path, 27 MiB)
    gemm_nt<false><<<dim3(16, 32), blk, 0, stream>>>(h, D_, qw, D_, qb, nullptr, nullptr,
                                                     qscr, MTOK, 2048, 2048);
    gemm_nt<false><<<dim3(4, 32), blk, 0, stream>>>(h, D_, kw, D_, kb, nullptr, nullptr,
                                                    kbuf, MTOK, 512, 2048);
    gemm_nt<false><<<dim3(4, 32), blk, 0, stream>>>(h, D_, vw, D_, vbi, nullptr, nullptr,
                                                    vbuf, MTOK, 512, 2048);
    transpose_v<<<dim3(32, 2, 8), blk, 0, stream>>>(vbuf, vt);
    attn_k<<<dim3(32, 32), blk, 0, stream>>>(qscr, kbuf, vt, h);
    gemm_nt<true><<<dim3(16, 32), blk, 0, stream>>>(h, D_, ow, D_, nullptr, x, nullptr,
                                                    d_out, MTOK, 2048, 2048);
    rmsnorm_k<<<MTOK, blk, 0, stream>>>(out, ln2w, h);
    for (int fc = 0; fc < 4; ++fc) {
      const float* gwc = gw + (size_t)fc * FC_ * D_;
      const float* uwc = uw + (size_t)fc * FC_ * D_;
      const float* dwc = dw + (size_t)fc * FC_;
      gemm_nt<false><<<dim3(11, 32), blk, 0, stream>>>(h, D_, gwc, D_, nullptr, nullptr,
                                                       nullptr, g, MTOK, FC_, 2048);
      gemm_nt<false><<<dim3(11, 32), blk, 0, stream>>>(h, D_, uwc, D_, nullptr, nullptr,
                                                       g, g, MTOK, FC_, 2048);
      gemm_nt<true><<<dim3(16, 32), blk, 0, stream>>>(g, FC_, dwc, F_, nullptr, out,
                                                      nullptr, d_out, MTOK, 2048, FC_);
    }
  }
}

// Round 2
// 1343.394 us; speedup vs baseline: 1.1243x; 1.0387x over previous
//
#include <hip/hip_runtime.h>

typedef unsigned short u16;
typedef __attribute__((ext_vector_type(8))) short s8v;   // 8 x bf16 (4 VGPRs)
typedef __attribute__((ext_vector_type(4))) float f4v;   // MFMA acc

#define MFMA16(a, b, c) __builtin_amdgcn_mfma_f32_16x16x32_bf16(a, b, c, 0, 0, 0)

#define B_    2
#define L_    2048
#define D_    2048
#define H_    16
#define KVH_  4
#define HD_   128
#define F_    5632
#define FC_   1408        // F chunk (4 chunks)
#define MTOK  (B_ * L_)   // 4096
#define NEG_BIG (-1e30f)
#define SCL2E 0.127517416f   // 128^-0.5 * log2(e)

__device__ __forceinline__ float b2f(u16 h) {
  union { float f; unsigned u; } v; v.u = ((unsigned)h) << 16; return v.f;
}
__device__ __forceinline__ u16 f2b(float f) {
  union { float f; unsigned u; } v; v.f = f;
  unsigned r = v.u + 0x7FFFu + ((v.u >> 16) & 1u);
  return (u16)(r >> 16);
}
__device__ __forceinline__ s8v ld8(const u16* p) { return *reinterpret_cast<const s8v*>(p); }
__device__ __forceinline__ void st8(u16* p, s8v v) { *reinterpret_cast<s8v*>(p) = v; }
// async global->LDS, 16B per lane; lds dest = wave-uniform base + lane*16 [m97]
__device__ __forceinline__ void gld16(const u16* g, u16* l) {
  __builtin_amdgcn_global_load_lds((const __attribute__((address_space(1))) void*)g,
                                   (__attribute__((address_space(3))) void*)l, 16, 0, 0);
}

// ---------------- fp32 -> bf16 weight convert (grid-stride, 8/thread) -----
__global__ __launch_bounds__(256) void conv_k(const float* __restrict__ src,
                                              u16* __restrict__ dst, int n8) {
  int i = blockIdx.x * 256 + threadIdx.x;
  const int stride = gridDim.x * 256;
  for (; i < n8; i += stride) {
    const float* p = src + (size_t)i * 8;
    float4 a = *(const float4*)p, b = *(const float4*)(p + 4);
    float f[8] = {a.x, a.y, a.z, a.w, b.x, b.y, b.z, b.w};
    s8v o;
#pragma unroll
    for (int j = 0; j < 8; ++j) o[j] = (short)f2b(f[j]);
    st8(dst + (size_t)i * 8, o);
  }
}

// ---------------- RMSNorm: fp32 in -> bf16 out, one block per row ---------
__global__ __launch_bounds__(256) void rmsnorm_k(const float* __restrict__ x,
                                                 const float* __restrict__ w,
                                                 u16* __restrict__ out) {
  const int row = blockIdx.x, t = threadIdx.x;
  const float* xr = x + (size_t)row * D_ + t * 8;
  float4 a = *(const float4*)(xr);
  float4 b = *(const float4*)(xr + 4);
  float f[8] = {a.x, a.y, a.z, a.w, b.x, b.y, b.z, b.w};
  float ss = 0.f;
#pragma unroll
  for (int j = 0; j < 8; ++j) ss += f[j] * f[j];
#pragma unroll
  for (int m = 1; m < 64; m <<= 1) ss += __shfl_xor(ss, m);
  __shared__ float red[4];
  if ((t & 63) == 0) red[t >> 6] = ss;
  __syncthreads();
  float tot = red[0] + red[1] + red[2] + red[3];
  float inv = rsqrtf(tot * (1.f / D_) + 1e-6f);
  float4 wa = *(const float4*)(w + t * 8);
  float4 wb = *(const float4*)(w + t * 8 + 4);
  float wf[8] = {wa.x, wa.y, wa.z, wa.w, wb.x, wb.y, wb.z, wb.w};
  s8v o;
#pragma unroll
  for (int j = 0; j < 8; ++j) o[j] = (short)f2b(f[j] * inv * wf[j]);
  st8(out + (size_t)row * D_ + t * 8, o);
}

// ======== GEMM variant 1: A bf16, W bf16, global_load_lds staging =========
// C[M,N] = A[M,:K] * W[N,:K]^T
// v2: triple-buffered depth-2 prefetch pipeline (T3+T4): raw s_barrier +
// counted vmcnt (never 0 mid-loop) so a single block flows without relying
// on co-resident blocks to hide the staging drain (grids here are only
// 1-2 blocks/CU; the old __syncthreads vmcnt(0)-drain was fully exposed).
template <bool C_F32>
__global__ __launch_bounds__(256) void gemm_bb(const u16* __restrict__ A, int lda,
                                               const u16* __restrict__ W, int ldw,
                                               const float* __restrict__ bias,
                                               const float* resid,
                                               const u16* gatein,
                                               void* Cv,
                                               int M, int N, int K) {
  __shared__ __align__(16) u16 As[3][128 * 32];
  __shared__ __align__(16) u16 Bs[3][128 * 32];
  const int t = threadIdx.x;
  const int l = t & 63, w = t >> 6;
  const int lr = l & 15, lg = l >> 4;
  const int m0 = blockIdx.y * 128, n0 = blockIdx.x * 128;
  const int wm = (w >> 1) * 64, wn = (w & 1) * 64;
  const int sr = t >> 2, sc = (t & 3) * 8;
  const u16* Ag0 = A + (size_t)(m0 + sr) * lda + sc;
  const u16* Ag1 = A + (size_t)(m0 + sr + 64) * lda + sc;
  const u16* Wg0 = W + (size_t)(n0 + sr) * ldw + sc;
  const u16* Wg1 = W + (size_t)(n0 + sr + 64) * ldw + sc;

  // wave-uniform LDS bases: thread t's 16B slot is at linear offset t*8 u16
  auto stage = [&](int buf, int koff) {
    gld16(Ag0 + koff, &As[buf][w * 512]);
    gld16(Ag1 + koff, &As[buf][2048 + w * 512]);
    gld16(Wg0 + koff, &Bs[buf][w * 512]);
    gld16(Wg1 + koff, &Bs[buf][2048 + w * 512]);
  };

  const f4v zero4 = {0.f, 0.f, 0.f, 0.f};
  f4v acc[4][4];
#pragma unroll
  for (int i = 0; i < 4; ++i)
#pragma unroll
    for (int j = 0; j < 4; ++j) acc[i][j] = zero4;

  stage(0, 0);
  if (K > 32) stage(1, 32);
  int cur = 0;
  for (int k0 = 0; k0 < K; k0 += 32) {
    const bool pf2 = (k0 + 64 < K);           // block-uniform
    if (pf2) {
      int nb = cur + 2; if (nb >= 3) nb -= 3;
      stage(nb, k0 + 64);
    }
    // wait for THIS tile's 4 loads: allow the (up to) 8 younger prefetch
    // loads to stay in flight across the barrier (T4).
    if (pf2)                   asm volatile("s_waitcnt vmcnt(8)" ::: "memory");
    else if (k0 + 32 < K)      asm volatile("s_waitcnt vmcnt(4)" ::: "memory");
    else                       asm volatile("s_waitcnt vmcnt(0)" ::: "memory");
    __builtin_amdgcn_s_barrier();             // all waves: cur tile valid
    s8v af[4], bf[4];
#pragma unroll
    for (int i = 0; i < 4; ++i) {
      af[i] = ld8(&As[cur][(wm + i * 16 + lr) * 32 + lg * 8]);
      bf[i] = ld8(&Bs[cur][(wn + i * 16 + lr) * 32 + lg * 8]);
    }
    __builtin_amdgcn_s_setprio(1);
#pragma unroll
    for (int i = 0; i < 4; ++i)
#pragma unroll
      for (int j = 0; j < 4; ++j)
        acc[i][j] = MFMA16(af[i], bf[j], acc[i][j]);
    __builtin_amdgcn_s_setprio(0);
    __builtin_amdgcn_s_barrier();             // all waves done reading cur
    ++cur; if (cur == 3) cur = 0;
  }
  // epilogue: C/D layout col = lane&15, row = (lane>>4)*4 + reg  [m89]
#pragma unroll
  for (int j = 0; j < 4; ++j) {
    const int col = n0 + wn + j * 16 + lr;
    const float bv = bias ? bias[col] : 0.f;
#pragma unroll
    for (int i = 0; i < 4; ++i) {
      const int row = m0 + wm + i * 16 + lg * 4;
#pragma unroll
      for (int r = 0; r < 4; ++r) {
        float vv = acc[i][j][r] + bv;
        size_t off = (size_t)(row + r) * N + col;
        if (gatein) {
          float gf = b2f(gatein[off]);
          vv *= gf / (1.f + __expf(-gf));   // silu(gate) * up
        }
        if (resid) vv += resid[off];
        if (C_F32) ((float*)Cv)[off] = vv;
        else       ((u16*)Cv)[off]   = f2b(vv);
      }
    }
  }
}

// ======== GEMM variant 2 (fallback): A bf16, W fp32 staged in regs ========
template <bool C_F32>
__global__ __launch_bounds__(256) void gemm_nt(const u16* __restrict__ A, int lda,
                                               const float* __restrict__ W, int ldw,
                                               const float* __restrict__ bias,
                                               const float* resid,
                                               const u16* gatein,
                                               void* Cv,
                                               int M, int N, int K) {
  __shared__ __align__(16) u16 As[128 * 32];
  __shared__ __align__(16) u16 Bs[128 * 32];
  const int t = threadIdx.x;
  const int l = t & 63, w = t >> 6;
  const int lr = l & 15, lg = l >> 4;
  const int m0 = blockIdx.y * 128, n0 = blockIdx.x * 128;
  const int wm = (w >> 1) * 64, wn = (w & 1) * 64;
  const int sr = t >> 2, sc = (t & 3) * 8;
  const u16* Ag0 = A + (size_t)(m0 + sr) * lda + sc;
  const u16* Ag1 = A + (size_t)(m0 + sr + 64) * lda + sc;
  const float* Wg0 = W + (size_t)(n0 + sr) * ldw + sc;
  const float* Wg1 = W + (size_t)(n0 + sr + 64) * ldw + sc;

  const f4v zero4 = {0.f, 0.f, 0.f, 0.f};
  f4v acc[4][4];
#pragma unroll
  for (int i = 0; i < 4; ++i)
#pragma unroll
    for (int j = 0; j < 4; ++j) acc[i][j] = zero4;

  for (int k0 = 0; k0 < K; k0 += 32) {
    s8v a0 = ld8(Ag0 + k0), a1 = ld8(Ag1 + k0);
    float4 w0a = *(const float4*)(Wg0 + k0), w0b = *(const float4*)(Wg0 + k0 + 4);
    float4 w1a = *(const float4*)(Wg1 + k0), w1b = *(const float4*)(Wg1 + k0 + 4);
    float wf0[8] = {w0a.x, w0a.y, w0a.z, w0a.w, w0b.x, w0b.y, w0b.z, w0b.w};
    float wf1[8] = {w1a.x, w1a.y, w1a.z, w1a.w, w1b.x, w1b.y, w1b.z, w1b.w};
    s8v b0, b1;
#pragma unroll
    for (int j = 0; j < 8; ++j) { b0[j] = (short)f2b(wf0[j]); b1[j] = (short)f2b(wf1[j]); }
    __syncthreads();
    st8(&As[sr * 32 + sc], a0);
    st8(&As[(sr + 64) * 32 + sc], a1);
    st8(&Bs[sr * 32 + sc], b0);
    st8(&Bs[(sr + 64) * 32 + sc], b1);
    __syncthreads();
    s8v af[4], bf[4];
#pragma unroll
    for (int i = 0; i < 4; ++i) {
      af[i] = ld8(&As[(wm + i * 16 + lr) * 32 + lg * 8]);
      bf[i] = ld8(&Bs[(wn + i * 16 + lr) * 32 + lg * 8]);
    }
#pragma unroll
    for (int i = 0; i < 4; ++i)
#pragma unroll
      for (int j = 0; j < 4; ++j)
        acc[i][j] = MFMA16(af[i], bf[j], acc[i][j]);
  }
#pragma unroll
  for (int j = 0; j < 4; ++j) {
    const int col = n0 + wn + j * 16 + lr;
    const float bv = bias ? bias[col] : 0.f;
#pragma unroll
    for (int i = 0; i < 4; ++i) {
      const int row = m0 + wm + i * 16 + lg * 4;
#pragma unroll
      for (int r = 0; r < 4; ++r) {
        float vv = acc[i][j][r] + bv;
        size_t off = (size_t)(row + r) * N + col;
        if (gatein) {
          float gf = b2f(gatein[off]);
          vv *= gf / (1.f + __expf(-gf));
        }
        if (resid) vv += resid[off];
        if (C_F32) ((float*)Cv)[off] = vv;
        else       ((u16*)Cv)[off]   = f2b(vv);
      }
    }
  }
}

// ---------------- V transpose: bf16 [B,L,512] -> VT [B][KVH][HD][L] -------
__global__ __launch_bounds__(256) void transpose_v(const u16* __restrict__ V,
                                                   u16* __restrict__ VT) {
  __shared__ u16 tile[64][72];
  const int t = threadIdx.x;
  const int tok0 = blockIdx.x * 64;
  const int hd0 = blockIdx.y * 64;
  const int bk = blockIdx.z;           // b*KVH + kvh
  const int b = bk >> 2, kvh = bk & 3;
#pragma unroll
  for (int c = 0; c < 16; ++c) {
    int idx = t + c * 256;
    int tok = idx >> 6, hd = idx & 63;
    tile[tok][hd] = V[(size_t)(b * L_ + tok0 + tok) * 512 + kvh * 128 + hd0 + hd];
  }
  __syncthreads();
#pragma unroll
  for (int c = 0; c < 16; ++c) {
    int idx = t + c * 256;
    int tok = idx & 63, hd = idx >> 6;
    VT[(size_t)(bk * 128 + hd0 + hd) * L_ + tok0 + tok] = tile[tok][hd];
  }
}

// ---------------- Flash attention, causal, GQA (kv = h % 4), all bf16 -----
// q-tile 64, 4 waves (wave w owns q rows w*16..+15), k-tiles of 64 keys.
// double-buffered global_load_lds staging (2-phase pipeline, T3/T14),
// XOR-swizzled K/V tiles (linear dest + pre-swizzled source, rule 21),
// reversed q-tile launch order (long causal blocks first), setprio (T5).
__global__ __launch_bounds__(256) void attn_k(const u16* __restrict__ Q,
                                              const u16* __restrict__ Kx,
                                              const u16* __restrict__ VT,
                                              u16* __restrict__ O) {
  __shared__ __align__(16) u16 KtB[2][64 * 128];   // [key][hd], swizzled
  __shared__ __align__(16) u16 VtB[2][128 * 64];   // [hd][key], swizzled
  __shared__ __align__(16) u16 Pb[4 * 16 * 72];    // per-wave [qlocal][key]
  const int t = threadIdx.x, l = t & 63, w = t >> 6;
  const int lr = l & 15, lg = l >> 4;
  const int bh = blockIdx.y, b = bh >> 4, h = bh & 15, kvh = h & 3;
  const int qt = (int)gridDim.x - 1 - blockIdx.x;  // heavy blocks dispatch first
  const int q0 = qt * 64;
  const int ktmax = qt;
  const f4v zero4 = {0.f, 0.f, 0.f, 0.f};

  // staging geometry: linear LDS dest (idx = c*256+t, 16B chunks);
  // source column pre-XOR'd so a swizzled read is conflict-free.
  const int kxr = t >> 4;                     // K: row-in-group 0..15
  const int kxc = (t & 15) ^ (kxr & 7);       // K: swizzled 16B chunk 0..15
  const int vxr = t >> 3;                     // V: row-in-group 0..31
  const int vxc = (t & 7) ^ (vxr & 7);        // V: swizzled 16B chunk 0..7
  const u16* Kg = Kx + (size_t)(b * L_) * 512 + kvh * 128;
  const u16* Vg = VT + (size_t)((b * 4 + kvh) * 128) * L_;

  auto stage = [&](int ktile, int bufi) {
#pragma unroll
    for (int c = 0; c < 4; ++c)
      gld16(Kg + (size_t)(ktile * 64 + c * 16 + kxr) * 512 + kxc * 8,
            &KtB[bufi][c * 2048 + w * 512]);
#pragma unroll
    for (int c = 0; c < 4; ++c)
      gld16(Vg + (size_t)(c * 32 + vxr) * L_ + ktile * 64 + vxc * 8,
            &VtB[bufi][c * 2048 + w * 512]);
  };

  // Q fragments (A-layout: m = lane&15, k = (lane>>4)*8+j)
  s8v qf[4];
#pragma unroll
  for (int kf = 0; kf < 4; ++kf)
    qf[kf] = ld8(Q + (size_t)(b * L_ + q0 + w * 16 + lr) * 2048 +
                 h * 128 + kf * 32 + lg * 8);

  float mrow[4], srow[4];
  f4v oacc[8];
#pragma unroll
  for (int r = 0; r < 4; ++r) { mrow[r] = NEG_BIG; srow[r] = 0.f; }
#pragma unroll
  for (int n = 0; n < 8; ++n) oacc[n] = zero4;
  u16* Pw = Pb + w * 16 * 72;

  int cur = 0;
  stage(0, 0);
  asm volatile("s_waitcnt vmcnt(0)" ::: "memory");
  __syncthreads();

  for (int kt = 0; kt <= ktmax; ++kt) {
    if (kt < ktmax) stage(kt + 1, cur ^ 1);   // async prefetch next tile

    // S = Q K^T  (1 mf x 4 nf, K=128 via 4 kf)
    f4v s[4];
#pragma unroll
    for (int nf = 0; nf < 4; ++nf) s[nf] = zero4;
    __builtin_amdgcn_s_setprio(1);
#pragma unroll
    for (int nf = 0; nf < 4; ++nf)
#pragma unroll
      for (int kf = 0; kf < 4; ++kf) {
        s8v bfr = ld8(&KtB[cur][(nf * 16 + lr) * 128 +
                                ((kf * 4 + lg) ^ (lr & 7)) * 8]);
        s[nf] = MFMA16(qf[kf], bfr, s[nf]);
      }
    __builtin_amdgcn_s_setprio(0);

    const bool needmask = (kt == ktmax);
#pragma unroll
    for (int nf = 0; nf < 4; ++nf)
#pragma unroll
      for (int r = 0; r < 4; ++r) {
        float vv = s[nf][r] * SCL2E;
        if (needmask) {
          int key = kt * 64 + nf * 16 + lr;
          int qr = q0 + w * 16 + lg * 4 + r;
          if (key > qr) vv = NEG_BIG;
        }
        s[nf][r] = vv;
      }

    // row max (16 lr-lanes x 4 nf)
    float tm[4];
#pragma unroll
    for (int r = 0; r < 4; ++r) {
      float m = fmaxf(fmaxf(s[0][r], s[1][r]), fmaxf(s[2][r], s[3][r]));
#pragma unroll
      for (int msk = 1; msk < 16; msk <<= 1) m = fmaxf(m, __shfl_xor(m, msk));
      tm[r] = m;
    }
    float al[4], rs[4];
#pragma unroll
    for (int r = 0; r < 4; ++r) {
      float mn = fmaxf(mrow[r], tm[r]);
      al[r] = exp2f(mrow[r] - mn);
      mrow[r] = mn;
      rs[r] = 0.f;
    }
    // P = exp2(S - m); bf16 P to per-wave LDS (wave-private, in-order DS)
#pragma unroll
    for (int nf = 0; nf < 4; ++nf)
#pragma unroll
      for (int r = 0; r < 4; ++r) {
        float p = exp2f(s[nf][r] - mrow[r]);
        rs[r] += p;
        Pw[(lg * 4 + r) * 72 + nf * 16 + lr] = f2b(p);
      }
#pragma unroll
    for (int r = 0; r < 4; ++r) {
#pragma unroll
      for (int msk = 1; msk < 16; msk <<= 1) rs[r] += __shfl_xor(rs[r], msk);
      srow[r] = srow[r] * al[r] + rs[r];
    }
#pragma unroll
    for (int n = 0; n < 8; ++n)
#pragma unroll
      for (int r = 0; r < 4; ++r) oacc[n][r] *= al[r];

    // O += P V
    s8v pa[2];
#pragma unroll
    for (int k2 = 0; k2 < 2; ++k2)
      pa[k2] = ld8(&Pw[lr * 72 + k2 * 32 + lg * 8]);
    __builtin_amdgcn_s_setprio(1);
#pragma unroll
    for (int n = 0; n < 8; ++n)
#pragma unroll
      for (int k2 = 0; k2 < 2; ++k2) {
        s8v vb = ld8(&VtB[cur][(n * 16 + lr) * 64 +
                               ((k2 * 4 + lg) ^ (lr & 7)) * 8]);
        oacc[n] = MFMA16(pa[k2], vb, oacc[n]);
      }
    __builtin_amdgcn_s_setprio(0);

    asm volatile("s_waitcnt vmcnt(0)" ::: "memory");  // prefetch landed
    __syncthreads();                                   // all waves done w/ cur
    cur ^= 1;
  }

  // normalize + store (bf16)
#pragma unroll
  for (int r = 0; r < 4; ++r) {
    float inv = 1.f / srow[r];
#pragma unroll
    for (int n = 0; n < 8; ++n) {
      size_t off = (size_t)(b * L_ + q0 + w * 16 + lg * 4 + r) * 2048 +
                   h * 128 + n * 16 + lr;
      O[off] = f2b(oacc[n][r] * inv);
    }
  }
}

// ---------------- launch ---------------------------------------------------
extern "C" void kernel_launch(void* const* d_in, const int* in_sizes, int n_in,
                              void* d_out, int out_size, void* d_ws, size_t ws_size,
                              hipStream_t stream) {
  const float* x    = (const float*)d_in[0];
  const float* ln1w = (const float*)d_in[1];
  const float* qw   = (const float*)d_in[2];
  const float* qb   = (const float*)d_in[3];
  const float* kw   = (const float*)d_in[4];
  const float* kb   = (const float*)d_in[5];
  const float* vw   = (const float*)d_in[6];
  const float* vbi  = (const float*)d_in[7];
  const float* ow   = (const float*)d_in[8];
  const float* ln2w = (const float*)d_in[9];
  const float* gw   = (const float*)d_in[10];
  const float* uw   = (const float*)d_in[11];
  const float* dw   = (const float*)d_in[12];
  float* out = (float*)d_out;

  char* ws = (char*)d_ws;
  u16* h    = (u16*)(ws);                  // 16 MiB
  u16* kbuf = (u16*)(ws + (16ull << 20));  // 4 MiB
  u16* vbuf = (u16*)(ws + (20ull << 20));  // 4 MiB
  u16* vt   = (u16*)(ws + (24ull << 20));  // 4 MiB
  u16* g    = (u16*)(ws + (16ull << 20));  // 11 MiB (phase C, reuses kb/vb)
  u16* qscr = (u16*)d_out;                 // bf16 Q scratch in d_out (16 MiB)

  dim3 blk(256);
  const bool big = ws_size >= 119537664ull;   // bf16-weight path needs ~114 MiB

  rmsnorm_k<<<MTOK, blk, 0, stream>>>(x, ln1w, h);

  if (big) {
    // bf16 weight pool at +28 MiB
    u16* wp = (u16*)(ws + (28ull << 20));
    u16* wq = wp;                          // 4,194,304 elems
    u16* wk = wq + 4194304;                // 1,048,576
    u16* wv = wk + 1048576;                // 1,048,576
    u16* wo = wv + 1048576;                // 4,194,304
    u16* wg = wo + 4194304;                // 11,534,336
    u16* wu = wg + 11534336;               // 11,534,336
    u16* wd = wu + 11534336;               // 11,534,336
    conv_k<<<2048, blk, 0, stream>>>(qw, wq, 4194304 / 8);
    conv_k<<<512, blk, 0, stream>>>(kw, wk, 1048576 / 8);
    conv_k<<<512, blk, 0, stream>>>(vw, wv, 1048576 / 8);
    conv_k<<<2048, blk, 0, stream>>>(ow, wo, 4194304 / 8);
    conv_k<<<2048, blk, 0, stream>>>(gw, wg, 11534336 / 8);
    conv_k<<<2048, blk, 0, stream>>>(uw, wu, 11534336 / 8);
    conv_k<<<2048, blk, 0, stream>>>(dw, wd, 11534336 / 8);

    gemm_bb<false><<<dim3(16, 32), blk, 0, stream>>>(h, D_, wq, D_, qb, nullptr, nullptr,
                                                     qscr, MTOK, 2048, 2048);
    gemm_bb<false><<<dim3(4, 32), blk, 0, stream>>>(h, D_, wk, D_, kb, nullptr, nullptr,
                                                    kbuf, MTOK, 512, 2048);
    gemm_bb<false><<<dim3(4, 32), blk, 0, stream>>>(h, D_, wv, D_, vbi, nullptr, nullptr,
                                                    vbuf, MTOK, 512, 2048);
    transpose_v<<<dim3(32, 2, 8), blk, 0, stream>>>(vbuf, vt);
    attn_k<<<dim3(32, 32), blk, 0, stream>>>(qscr, kbuf, vt, h);
    gemm_bb<true><<<dim3(16, 32), blk, 0, stream>>>(h, D_, wo, D_, nullptr, x, nullptr,
                                                    d_out, MTOK, 2048, 2048);
    rmsnorm_k<<<MTOK, blk, 0, stream>>>(out, ln2w, h);
    for (int fc = 0; fc < 4; ++fc) {
      const u16* gwc = wg + (size_t)fc * FC_ * D_;
      const u16* uwc = wu + (size_t)fc * FC_ * D_;
      const u16* dwc = wd + (size_t)fc * FC_;
      gemm_bb<false><<<dim3(11, 32), blk, 0, stream>>>(h, D_, gwc, D_, nullptr, nullptr,
                                                       nullptr, g, MTOK, FC_, 2048);
      gemm_bb<false><<<dim3(11, 32), blk, 0, stream>>>(h, D_, uwc, D_, nullptr, nullptr,
                                                       g, g, MTOK, FC_, 2048);
      gemm_bb<true><<<dim3(16, 32), blk, 0, stream>>>(g, FC_, dwc, F_, nullptr, out,
                                                      nullptr, d_out, MTOK, 2048, FC_);
    }
  } else {
    // fallback: fp32-weight register staging (round-4 proven path, 27 MiB)
    gemm_nt<false><<<dim3(16, 32), blk, 0, stream>>>(h, D_, qw, D_, qb, nullptr, nullptr,
                                                     qscr, MTOK, 2048, 2048);
    gemm_nt<false><<<dim3(4, 32), blk, 0, stream>>>(h, D_, kw, D_, kb, nullptr, nullptr,
                                                    kbuf, MTOK, 512, 2048);
    gemm_nt<false><<<dim3(4, 32), blk, 0, stream>>>(h, D_, vw, D_, vbi, nullptr, nullptr,
                                                    vbuf, MTOK, 512, 2048);
    transpose_v<<<dim3(32, 2, 8), blk, 0, stream>>>(vbuf, vt);
    attn_k<<<dim3(32, 32), blk, 0, stream>>>(qscr, kbuf, vt, h);
    gemm_nt<true><<<dim3(16, 32), blk, 0, stream>>>(h, D_, ow, D_, nullptr, x, nullptr,
                                                    d_out, MTOK, 2048, 2048);
    rmsnorm_k<<<MTOK, blk, 0, stream>>>(out, ln2w, h);
    for (int fc = 0; fc < 4; ++fc) {
      const float* gwc = gw + (size_t)fc * FC_ * D_;
      const float* uwc = uw + (size_t)fc * FC_ * D_;
      const float* dwc = dw + (size_t)fc * FC_;
      gemm_nt<false><<<dim3(11, 32), blk, 0, stream>>>(h, D_, gwc, D_, nullptr, nullptr,
                                                       nullptr, g, MTOK, FC_, 2048);
      gemm_nt<false><<<dim3(11, 32), blk, 0, stream>>>(h, D_, uwc, D_, nullptr, nullptr,
                                                       g, g, MTOK, FC_, 2048);
      gemm_nt<true><<<dim3(16, 32), blk, 0, stream>>>(g, FC_, dwc, F_, nullptr, out,
                                                      nullptr, d_out, MTOK, 2048, FC_);
    }
  }
}

// Round 3
// 1303.560 us; speedup vs baseline: 1.1586x; 1.0306x over previous
//
#include <hip/hip_runtime.h>

typedef unsigned short u16;
typedef __attribute__((ext_vector_type(8))) short s8v;   // 8 x bf16 (4 VGPRs)
typedef __attribute__((ext_vector_type(4))) float f4v;   // MFMA acc

#define MFMA16(a, b, c) __builtin_amdgcn_mfma_f32_16x16x32_bf16(a, b, c, 0, 0, 0)

#define B_    2
#define L_    2048
#define D_    2048
#define H_    16
#define KVH_  4
#define HD_   128
#define F_    5632
#define FC_   1408        // F chunk (4 chunks)
#define MTOK  (B_ * L_)   // 4096
#define NEG_BIG (-1e30f)
#define SCL2E 0.127517416f   // 128^-0.5 * log2(e)

__device__ __forceinline__ float b2f(u16 h) {
  union { float f; unsigned u; } v; v.u = ((unsigned)h) << 16; return v.f;
}
__device__ __forceinline__ u16 f2b(float f) {
  union { float f; unsigned u; } v; v.f = f;
  unsigned r = v.u + 0x7FFFu + ((v.u >> 16) & 1u);
  return (u16)(r >> 16);
}
__device__ __forceinline__ s8v ld8(const u16* p) { return *reinterpret_cast<const s8v*>(p); }
__device__ __forceinline__ void st8(u16* p, s8v v) { *reinterpret_cast<s8v*>(p) = v; }
// async global->LDS, 16B per lane; lds dest = wave-uniform base + lane*16 [m97]
__device__ __forceinline__ void gld16(const u16* g, u16* l) {
  __builtin_amdgcn_global_load_lds((const __attribute__((address_space(1))) void*)g,
                                   (__attribute__((address_space(3))) void*)l, 16, 0, 0);
}

// ---------------- fp32 -> bf16 weight convert (grid-stride, 8/thread) -----
__global__ __launch_bounds__(256) void conv_k(const float* __restrict__ src,
                                              u16* __restrict__ dst, int n8) {
  int i = blockIdx.x * 256 + threadIdx.x;
  const int stride = gridDim.x * 256;
  for (; i < n8; i += stride) {
    const float* p = src + (size_t)i * 8;
    float4 a = *(const float4*)p, b = *(const float4*)(p + 4);
    float f[8] = {a.x, a.y, a.z, a.w, b.x, b.y, b.z, b.w};
    s8v o;
#pragma unroll
    for (int j = 0; j < 8; ++j) o[j] = (short)f2b(f[j]);
    st8(dst + (size_t)i * 8, o);
  }
}

// ---------------- concat q/k/v bias into [3072] ---------------------------
__global__ __launch_bounds__(256) void catbias_k(const float* __restrict__ qb,
                                                 const float* __restrict__ kb,
                                                 const float* __restrict__ vb,
                                                 float* __restrict__ o) {
  int i = blockIdx.x * 256 + threadIdx.x;
  float v;
  if (i < 2048) v = qb[i];
  else if (i < 2560) v = kb[i - 2048];
  else v = vb[i - 2560];
  o[i] = v;
}

// ---------------- RMSNorm: fp32 in -> bf16 out, one block per row ---------
__global__ __launch_bounds__(256) void rmsnorm_k(const float* __restrict__ x,
                                                 const float* __restrict__ w,
                                                 u16* __restrict__ out) {
  const int row = blockIdx.x, t = threadIdx.x;
  const float* xr = x + (size_t)row * D_ + t * 8;
  float4 a = *(const float4*)(xr);
  float4 b = *(const float4*)(xr + 4);
  float f[8] = {a.x, a.y, a.z, a.w, b.x, b.y, b.z, b.w};
  float ss = 0.f;
#pragma unroll
  for (int j = 0; j < 8; ++j) ss += f[j] * f[j];
#pragma unroll
  for (int m = 1; m < 64; m <<= 1) ss += __shfl_xor(ss, m);
  __shared__ float red[4];
  if ((t & 63) == 0) red[t >> 6] = ss;
  __syncthreads();
  float tot = red[0] + red[1] + red[2] + red[3];
  float inv = rsqrtf(tot * (1.f / D_) + 1e-6f);
  float4 wa = *(const float4*)(w + t * 8);
  float4 wb = *(const float4*)(w + t * 8 + 4);
  float wf[8] = {wa.x, wa.y, wa.z, wa.w, wb.x, wb.y, wb.z, wb.w};
  s8v o;
#pragma unroll
  for (int j = 0; j < 8; ++j) o[j] = (short)f2b(f[j] * inv * wf[j]);
  st8(out + (size_t)row * D_ + t * 8, o);
}

// ======== GEMM variant 1: A bf16, W bf16, global_load_lds staging =========
// C[M=4096,N] = A[M,:K] * W[N,:K]^T
// v3: single-barrier triple-buffered depth-2 pipeline (T3+T4, counted vmcnt
//     never 0 mid-loop); T2 LDS chunk-XOR swizzle (pre-swizzled global source
//     since global_load_lds dest must be linear, rule 21) kills the 8-way
//     ds_read_b128 row-stride-64B bank conflict; T1 XCD-aware bijective block
//     remap (m204) with n-outer/m-inner so each XCD's L2 holds one W panel.
// 1-D grid: gridDim.x = 32 * (N/128).
template <bool C_F32>
__global__ __launch_bounds__(256) void gemm_bb(const u16* __restrict__ A, int lda,
                                               const u16* __restrict__ W, int ldw,
                                               const float* __restrict__ bias,
                                               const float* resid,
                                               const u16* gatein,
                                               void* Cv,
                                               int N, int K) {
  __shared__ __align__(16) u16 As[3][128 * 32];
  __shared__ __align__(16) u16 Bs[3][128 * 32];
  const int t = threadIdx.x;
  const int l = t & 63, w = t >> 6;
  const int lr = l & 15, lg = l >> 4;
  // T1: bijective XCD chunk remap; pos enumerated n-outer, m-inner (M/128=32)
  const int total = gridDim.x;
  const int qd = total >> 3, rr = total & 7;
  const int xc = blockIdx.x & 7, xi = blockIdx.x >> 3;
  const int pos = xc * qd + (xc < rr ? xc : rr) + xi;
  const int m0 = (pos & 31) * 128;
  const int n0 = (pos >> 5) * 128;
  const int wm = (w >> 1) * 64, wn = (w & 1) * 64;
  // staging: thread t owns 16B chunk (row sr, phys chunk t&3); fetch the
  // LOGICAL chunk (t&3)^((sr>>1)&3) so physical layout is XOR-swizzled.
  const int sr = t >> 2;
  const int sc = (((t & 3) ^ ((t >> 3) & 3)) * 8);
  const u16* Ag0 = A + (size_t)(m0 + sr) * lda + sc;
  const u16* Ag1 = A + (size_t)(m0 + sr + 64) * lda + sc;
  const u16* Wg0 = W + (size_t)(n0 + sr) * ldw + sc;
  const u16* Wg1 = W + (size_t)(n0 + sr + 64) * ldw + sc;

  auto stage = [&](int buf, int koff) {
    gld16(Ag0 + koff, &As[buf][w * 512]);
    gld16(Ag1 + koff, &As[buf][2048 + w * 512]);
    gld16(Wg0 + koff, &Bs[buf][w * 512]);
    gld16(Wg1 + koff, &Bs[buf][2048 + w * 512]);
  };

  const f4v zero4 = {0.f, 0.f, 0.f, 0.f};
  f4v acc[4][4];
#pragma unroll
  for (int i = 0; i < 4; ++i)
#pragma unroll
    for (int j = 0; j < 4; ++j) acc[i][j] = zero4;

  // read-side chunk XOR: (row>>1)&3 == (lr>>1)&3 for all frag rows here
  const int xq = (lr >> 1) & 3;
  const int cofA = (lg ^ xq) * 8;

  stage(0, 0);
  if (K > 32) stage(1, 32);
  int cur = 0;
  for (int k0 = 0; k0 < K; k0 += 32) {
    // own tile-k loads done (outstanding: k (4) + k+1 (4) -> keep 4 in flight)
    if (k0 + 32 < K) asm volatile("s_waitcnt vmcnt(4)" ::: "memory");
    else             asm volatile("s_waitcnt vmcnt(0)" ::: "memory");
    __builtin_amdgcn_s_barrier();          // all waves' tile-k DMA landed;
                                           // also: all step k-1 reads done
    if (k0 + 64 < K) {                     // stage tile k+2 into buf read @k-1
      int nb = cur + 2; if (nb >= 3) nb -= 3;
      stage(nb, k0 + 64);
    }
    s8v af[4], bf[4];
#pragma unroll
    for (int i = 0; i < 4; ++i) {
      af[i] = ld8(&As[cur][(wm + i * 16 + lr) * 32 + cofA]);
      bf[i] = ld8(&Bs[cur][(wn + i * 16 + lr) * 32 + cofA]);
    }
    __builtin_amdgcn_s_setprio(1);
#pragma unroll
    for (int i = 0; i < 4; ++i)
#pragma unroll
      for (int j = 0; j < 4; ++j)
        acc[i][j] = MFMA16(af[i], bf[j], acc[i][j]);
    __builtin_amdgcn_s_setprio(0);
    ++cur; if (cur == 3) cur = 0;
  }
  // epilogue: C/D layout col = lane&15, row = (lane>>4)*4 + reg  [m89]
#pragma unroll
  for (int j = 0; j < 4; ++j) {
    const int col = n0 + wn + j * 16 + lr;
    const float bv = bias ? bias[col] : 0.f;
#pragma unroll
    for (int i = 0; i < 4; ++i) {
      const int row = m0 + wm + i * 16 + lg * 4;
#pragma unroll
      for (int r = 0; r < 4; ++r) {
        float vv = acc[i][j][r] + bv;
        size_t off = (size_t)(row + r) * N + col;
        if (gatein) {
          float gf = b2f(gatein[off]);
          vv *= gf / (1.f + __expf(-gf));   // silu(gate) * up
        }
        if (resid) vv += resid[off];
        if (C_F32) ((float*)Cv)[off] = vv;
        else       ((u16*)Cv)[off]   = f2b(vv);
      }
    }
  }
}

// ======== GEMM variant 2 (fallback): A bf16, W fp32 staged in regs ========
template <bool C_F32>
__global__ __launch_bounds__(256) void gemm_nt(const u16* __restrict__ A, int lda,
                                               const float* __restrict__ W, int ldw,
                                               const float* __restrict__ bias,
                                               const float* resid,
                                               const u16* gatein,
                                               void* Cv,
                                               int M, int N, int K) {
  __shared__ __align__(16) u16 As[128 * 32];
  __shared__ __align__(16) u16 Bs[128 * 32];
  const int t = threadIdx.x;
  const int l = t & 63, w = t >> 6;
  const int lr = l & 15, lg = l >> 4;
  const int m0 = blockIdx.y * 128, n0 = blockIdx.x * 128;
  const int wm = (w >> 1) * 64, wn = (w & 1) * 64;
  const int sr = t >> 2, sc = (t & 3) * 8;
  const u16* Ag0 = A + (size_t)(m0 + sr) * lda + sc;
  const u16* Ag1 = A + (size_t)(m0 + sr + 64) * lda + sc;
  const float* Wg0 = W + (size_t)(n0 + sr) * ldw + sc;
  const float* Wg1 = W + (size_t)(n0 + sr + 64) * ldw + sc;

  const f4v zero4 = {0.f, 0.f, 0.f, 0.f};
  f4v acc[4][4];
#pragma unroll
  for (int i = 0; i < 4; ++i)
#pragma unroll
    for (int j = 0; j < 4; ++j) acc[i][j] = zero4;

  for (int k0 = 0; k0 < K; k0 += 32) {
    s8v a0 = ld8(Ag0 + k0), a1 = ld8(Ag1 + k0);
    float4 w0a = *(const float4*)(Wg0 + k0), w0b = *(const float4*)(Wg0 + k0 + 4);
    float4 w1a = *(const float4*)(Wg1 + k0), w1b = *(const float4*)(Wg1 + k0 + 4);
    float wf0[8] = {w0a.x, w0a.y, w0a.z, w0a.w, w0b.x, w0b.y, w0b.z, w0b.w};
    float wf1[8] = {w1a.x, w1a.y, w1a.z, w1a.w, w1b.x, w1b.y, w1b.z, w1b.w};
    s8v b0, b1;
#pragma unroll
    for (int j = 0; j < 8; ++j) { b0[j] = (short)f2b(wf0[j]); b1[j] = (short)f2b(wf1[j]); }
    __syncthreads();
    st8(&As[sr * 32 + sc], a0);
    st8(&As[(sr + 64) * 32 + sc], a1);
    st8(&Bs[sr * 32 + sc], b0);
    st8(&Bs[(sr + 64) * 32 + sc], b1);
    __syncthreads();
    s8v af[4], bf[4];
#pragma unroll
    for (int i = 0; i < 4; ++i) {
      af[i] = ld8(&As[(wm + i * 16 + lr) * 32 + lg * 8]);
      bf[i] = ld8(&Bs[(wn + i * 16 + lr) * 32 + lg * 8]);
    }
#pragma unroll
    for (int i = 0; i < 4; ++i)
#pragma unroll
      for (int j = 0; j < 4; ++j)
        acc[i][j] = MFMA16(af[i], bf[j], acc[i][j]);
  }
#pragma unroll
  for (int j = 0; j < 4; ++j) {
    const int col = n0 + wn + j * 16 + lr;
    const float bv = bias ? bias[col] : 0.f;
#pragma unroll
    for (int i = 0; i < 4; ++i) {
      const int row = m0 + wm + i * 16 + lg * 4;
#pragma unroll
      for (int r = 0; r < 4; ++r) {
        float vv = acc[i][j][r] + bv;
        size_t off = (size_t)(row + r) * N + col;
        if (gatein) {
          float gf = b2f(gatein[off]);
          vv *= gf / (1.f + __expf(-gf));
        }
        if (resid) vv += resid[off];
        if (C_F32) ((float*)Cv)[off] = vv;
        else       ((u16*)Cv)[off]   = f2b(vv);
      }
    }
  }
}

// ---------------- V transpose: bf16 [B,L,ldv] -> VT [B][KVH][HD][L] -------
__global__ __launch_bounds__(256) void transpose_v(const u16* __restrict__ V, int ldv,
                                                   u16* __restrict__ VT) {
  __shared__ u16 tile[64][72];
  const int t = threadIdx.x;
  const int tok0 = blockIdx.x * 64;
  const int hd0 = blockIdx.y * 64;
  const int bk = blockIdx.z;           // b*KVH + kvh
  const int b = bk >> 2, kvh = bk & 3;
#pragma unroll
  for (int c = 0; c < 16; ++c) {
    int idx = t + c * 256;
    int tok = idx >> 6, hd = idx & 63;
    tile[tok][hd] = V[(size_t)(b * L_ + tok0 + tok) * ldv + kvh * 128 + hd0 + hd];
  }
  __syncthreads();
#pragma unroll
  for (int c = 0; c < 16; ++c) {
    int idx = t + c * 256;
    int tok = idx & 63, hd = idx >> 6;
    VT[(size_t)(bk * 128 + hd0 + hd) * L_ + tok0 + tok] = tile[tok][hd];
  }
}

// ---------------- Flash attention, causal, GQA (kv = h % 4), all bf16 -----
// q-tile 64, 4 waves (wave w owns q rows w*16..+15), k-tiles of 64 keys.
// double-buffered global_load_lds staging (2-phase pipeline, T3/T14),
// XOR-swizzled K/V tiles (linear dest + pre-swizzled source, rule 21),
// reversed q-tile launch order (long causal blocks first), setprio (T5).
// Q/K read from strided buffers (qkv fused layout).
__global__ __launch_bounds__(256) void attn_k(const u16* __restrict__ Q, int ldq,
                                              const u16* __restrict__ Kx, int ldk,
                                              const u16* __restrict__ VT,
                                              u16* __restrict__ O) {
  __shared__ __align__(16) u16 KtB[2][64 * 128];   // [key][hd], swizzled
  __shared__ __align__(16) u16 VtB[2][128 * 64];   // [hd][key], swizzled
  __shared__ __align__(16) u16 Pb[4 * 16 * 72];    // per-wave [qlocal][key]
  const int t = threadIdx.x, l = t & 63, w = t >> 6;
  const int lr = l & 15, lg = l >> 4;
  const int bh = blockIdx.y, b = bh >> 4, h = bh & 15, kvh = h & 3;
  const int qt = (int)gridDim.x - 1 - blockIdx.x;  // heavy blocks dispatch first
  const int q0 = qt * 64;
  const int ktmax = qt;
  const f4v zero4 = {0.f, 0.f, 0.f, 0.f};

  // staging geometry: linear LDS dest (idx = c*256+t, 16B chunks);
  // source column pre-XOR'd so a swizzled read is conflict-free.
  const int kxr = t >> 4;                     // K: row-in-group 0..15
  const int kxc = (t & 15) ^ (kxr & 7);       // K: swizzled 16B chunk 0..15
  const int vxr = t >> 3;                     // V: row-in-group 0..31
  const int vxc = (t & 7) ^ (vxr & 7);        // V: swizzled 16B chunk 0..7
  const u16* Kg = Kx + (size_t)(b * L_) * ldk + kvh * 128;
  const u16* Vg = VT + (size_t)((b * 4 + kvh) * 128) * L_;

  auto stage = [&](int ktile, int bufi) {
#pragma unroll
    for (int c = 0; c < 4; ++c)
      gld16(Kg + (size_t)(ktile * 64 + c * 16 + kxr) * ldk + kxc * 8,
            &KtB[bufi][c * 2048 + w * 512]);
#pragma unroll
    for (int c = 0; c < 4; ++c)
      gld16(Vg + (size_t)(c * 32 + vxr) * L_ + ktile * 64 + vxc * 8,
            &VtB[bufi][c * 2048 + w * 512]);
  };

  // Q fragments (A-layout: m = lane&15, k = (lane>>4)*8+j)
  s8v qf[4];
#pragma unroll
  for (int kf = 0; kf < 4; ++kf)
    qf[kf] = ld8(Q + (size_t)(b * L_ + q0 + w * 16 + lr) * ldq +
                 h * 128 + kf * 32 + lg * 8);

  float mrow[4], srow[4];
  f4v oacc[8];
#pragma unroll
  for (int r = 0; r < 4; ++r) { mrow[r] = NEG_BIG; srow[r] = 0.f; }
#pragma unroll
  for (int n = 0; n < 8; ++n) oacc[n] = zero4;
  u16* Pw = Pb + w * 16 * 72;

  int cur = 0;
  stage(0, 0);
  asm volatile("s_waitcnt vmcnt(0)" ::: "memory");
  __syncthreads();

  for (int kt = 0; kt <= ktmax; ++kt) {
    if (kt < ktmax) stage(kt + 1, cur ^ 1);   // async prefetch next tile

    // S = Q K^T  (1 mf x 4 nf, K=128 via 4 kf)
    f4v s[4];
#pragma unroll
    for (int nf = 0; nf < 4; ++nf) s[nf] = zero4;
    __builtin_amdgcn_s_setprio(1);
#pragma unroll
    for (int nf = 0; nf < 4; ++nf)
#pragma unroll
      for (int kf = 0; kf < 4; ++kf) {
        s8v bfr = ld8(&KtB[cur][(nf * 16 + lr) * 128 +
                                ((kf * 4 + lg) ^ (lr & 7)) * 8]);
        s[nf] = MFMA16(qf[kf], bfr, s[nf]);
      }
    __builtin_amdgcn_s_setprio(0);

    const bool needmask = (kt == ktmax);
#pragma unroll
    for (int nf = 0; nf < 4; ++nf)
#pragma unroll
      for (int r = 0; r < 4; ++r) {
        float vv = s[nf][r] * SCL2E;
        if (needmask) {
          int key = kt * 64 + nf * 16 + lr;
          int qr = q0 + w * 16 + lg * 4 + r;
          if (key > qr) vv = NEG_BIG;
        }
        s[nf][r] = vv;
      }

    // row max (16 lr-lanes x 4 nf)
    float tm[4];
#pragma unroll
    for (int r = 0; r < 4; ++r) {
      float m = fmaxf(fmaxf(s[0][r], s[1][r]), fmaxf(s[2][r], s[3][r]));
#pragma unroll
      for (int msk = 1; msk < 16; msk <<= 1) m = fmaxf(m, __shfl_xor(m, msk));
      tm[r] = m;
    }
    float al[4], rs[4];
#pragma unroll
    for (int r = 0; r < 4; ++r) {
      float mn = fmaxf(mrow[r], tm[r]);
      al[r] = exp2f(mrow[r] - mn);
      mrow[r] = mn;
      rs[r] = 0.f;
    }
    // P = exp2(S - m); bf16 P to per-wave LDS (wave-private, in-order DS)
#pragma unroll
    for (int nf = 0; nf < 4; ++nf)
#pragma unroll
      for (int r = 0; r < 4; ++r) {
        float p = exp2f(s[nf][r] - mrow[r]);
        rs[r] += p;
        Pw[(lg * 4 + r) * 72 + nf * 16 + lr] = f2b(p);
      }
#pragma unroll
    for (int r = 0; r < 4; ++r) {
#pragma unroll
      for (int msk = 1; msk < 16; msk <<= 1) rs[r] += __shfl_xor(rs[r], msk);
      srow[r] = srow[r] * al[r] + rs[r];
    }
#pragma unroll
    for (int n = 0; n < 8; ++n)
#pragma unroll
      for (int r = 0; r < 4; ++r) oacc[n][r] *= al[r];

    // O += P V
    s8v pa[2];
#pragma unroll
    for (int k2 = 0; k2 < 2; ++k2)
      pa[k2] = ld8(&Pw[lr * 72 + k2 * 32 + lg * 8]);
    __builtin_amdgcn_s_setprio(1);
#pragma unroll
    for (int n = 0; n < 8; ++n)
#pragma unroll
      for (int k2 = 0; k2 < 2; ++k2) {
        s8v vb = ld8(&VtB[cur][(n * 16 + lr) * 64 +
                               ((k2 * 4 + lg) ^ (lr & 7)) * 8]);
        oacc[n] = MFMA16(pa[k2], vb, oacc[n]);
      }
    __builtin_amdgcn_s_setprio(0);

    asm volatile("s_waitcnt vmcnt(0)" ::: "memory");  // prefetch landed
    __syncthreads();                                   // all waves done w/ cur
    cur ^= 1;
  }

  // normalize + store (bf16)
#pragma unroll
  for (int r = 0; r < 4; ++r) {
    float inv = 1.f / srow[r];
#pragma unroll
    for (int n = 0; n < 8; ++n) {
      size_t off = (size_t)(b * L_ + q0 + w * 16 + lg * 4 + r) * 2048 +
                   h * 128 + n * 16 + lr;
      O[off] = f2b(oacc[n][r] * inv);
    }
  }
}

// ---------------- launch ---------------------------------------------------
extern "C" void kernel_launch(void* const* d_in, const int* in_sizes, int n_in,
                              void* d_out, int out_size, void* d_ws, size_t ws_size,
                              hipStream_t stream) {
  const float* x    = (const float*)d_in[0];
  const float* ln1w = (const float*)d_in[1];
  const float* qw   = (const float*)d_in[2];
  const float* qb   = (const float*)d_in[3];
  const float* kw   = (const float*)d_in[4];
  const float* kb   = (const float*)d_in[5];
  const float* vw   = (const float*)d_in[6];
  const float* vbi  = (const float*)d_in[7];
  const float* ow   = (const float*)d_in[8];
  const float* ln2w = (const float*)d_in[9];
  const float* gw   = (const float*)d_in[10];
  const float* uw   = (const float*)d_in[11];
  const float* dw   = (const float*)d_in[12];
  float* out = (float*)d_out;

  char* ws = (char*)d_ws;
  u16* h    = (u16*)(ws);                  // 16 MiB
  u16* kbuf = (u16*)(ws + (16ull << 20));  // 4 MiB (fallback only)
  u16* vbuf = (u16*)(ws + (20ull << 20));  // 4 MiB (fallback only)
  u16* vt   = (u16*)(ws + (24ull << 20));  // 4 MiB
  u16* g    = (u16*)(ws + (16ull << 20));  // 11 MiB (phase C, reuses kb/vb)
  u16* qscr = (u16*)d_out;                 // bf16 scratch in d_out

  dim3 blk(256);
  const bool big = ws_size >= 119537664ull;   // bf16-weight path needs ~114 MiB

  rmsnorm_k<<<MTOK, blk, 0, stream>>>(x, ln1w, h);

  if (big) {
    // bf16 weight pool at +28 MiB  (wq|wk|wv contiguous -> fused QKV weight)
    u16* wp = (u16*)(ws + (28ull << 20));
    u16* wq = wp;                          // 4,194,304 elems (2048 rows)
    u16* wk = wq + 4194304;                // 1,048,576     (512 rows)
    u16* wv = wk + 1048576;                // 1,048,576     (512 rows)
    u16* wo = wv + 1048576;                // 4,194,304
    u16* wg = wo + 4194304;                // 11,534,336
    u16* wu = wg + 11534336;               // 11,534,336
    u16* wd = wu + 11534336;               // 11,534,336
    conv_k<<<2048, blk, 0, stream>>>(qw, wq, 4194304 / 8);
    conv_k<<<512, blk, 0, stream>>>(kw, wk, 1048576 / 8);
    conv_k<<<512, blk, 0, stream>>>(vw, wv, 1048576 / 8);
    conv_k<<<2048, blk, 0, stream>>>(ow, wo, 4194304 / 8);
    conv_k<<<2048, blk, 0, stream>>>(gw, wg, 11534336 / 8);
    conv_k<<<2048, blk, 0, stream>>>(uw, wu, 11534336 / 8);
    conv_k<<<2048, blk, 0, stream>>>(dw, wd, 11534336 / 8);

    float* biasc = (float*)(ws + (16ull << 20));   // [3072] f32 (kbuf region)
    catbias_k<<<12, blk, 0, stream>>>(qb, kb, vbi, biasc);

    // fused QKV projection: C = [4096][3072] bf16 in d_out
    u16* qkv = (u16*)d_out;
    gemm_bb<false><<<768, blk, 0, stream>>>(h, D_, wq, D_, biasc, nullptr, nullptr,
                                            qkv, 3072, D_);
    transpose_v<<<dim3(32, 2, 8), blk, 0, stream>>>(qkv + 2560, 3072, vt);
    attn_k<<<dim3(32, 32), blk, 0, stream>>>(qkv, 3072, qkv + 2048, 3072, vt, h);
    gemm_bb<true><<<512, blk, 0, stream>>>(h, D_, wo, D_, nullptr, x, nullptr,
                                           d_out, 2048, D_);
    rmsnorm_k<<<MTOK, blk, 0, stream>>>(out, ln2w, h);
    for (int fc = 0; fc < 4; ++fc) {
      const u16* gwc = wg + (size_t)fc * FC_ * D_;
      const u16* uwc = wu + (size_t)fc * FC_ * D_;
      const u16* dwc = wd + (size_t)fc * FC_;
      gemm_bb<false><<<352, blk, 0, stream>>>(h, D_, gwc, D_, nullptr, nullptr,
                                              nullptr, g, FC_, D_);
      gemm_bb<false><<<352, blk, 0, stream>>>(h, D_, uwc, D_, nullptr, nullptr,
                                              g, g, FC_, D_);
      gemm_bb<true><<<512, blk, 0, stream>>>(g, FC_, dwc, F_, nullptr, out,
                                             nullptr, d_out, 2048, FC_);
    }
  } else {
    // fallback: fp32-weight register staging (round-4 proven path, 27 MiB)
    gemm_nt<false><<<dim3(16, 32), blk, 0, stream>>>(h, D_, qw, D_, qb, nullptr, nullptr,
                                                     qscr, MTOK, 2048, 2048);
    gemm_nt<false><<<dim3(4, 32), blk, 0, stream>>>(h, D_, kw, D_, kb, nullptr, nullptr,
                                                    kbuf, MTOK, 512, 2048);
    gemm_nt<false><<<dim3(4, 32), blk, 0, stream>>>(h, D_, vw, D_, vbi, nullptr, nullptr,
                                                    vbuf, MTOK, 512, 2048);
    transpose_v<<<dim3(32, 2, 8), blk, 0, stream>>>(vbuf, 512, vt);
    attn_k<<<dim3(32, 32), blk, 0, stream>>>(qscr, 2048, kbuf, 512, vt, h);
    gemm_nt<true><<<dim3(16, 32), blk, 0, stream>>>(h, D_, ow, D_, nullptr, x, nullptr,
                                                    d_out, MTOK, 2048, 2048);
    rmsnorm_k<<<MTOK, blk, 0, stream>>>(out, ln2w, h);
    for (int fc = 0; fc < 4; ++fc) {
      const float* gwc = gw + (size_t)fc * FC_ * D_;
      const float* uwc = uw + (size_t)fc * FC_ * D_;
      const float* dwc = dw + (size_t)fc * FC_;
      gemm_nt<false><<<dim3(11, 32), blk, 0, stream>>>(h, D_, gwc, D_, nullptr, nullptr,
                                                       nullptr, g, MTOK, FC_, 2048);
      gemm_nt<false><<<dim3(11, 32), blk, 0, stream>>>(h, D_, uwc, D_, nullptr, nullptr,
                                                       g, g, MTOK, FC_, 2048);
      gemm_nt<true><<<dim3(16, 32), blk, 0, stream>>>(g, FC_, dwc, F_, nullptr, out,
                                                      nullptr, d_out, MTOK, 2048, FC_);
    }
  }
}

// Round 4
// 1073.261 us; speedup vs baseline: 1.4072x; 1.2146x over previous
//
#include <hip/hip_runtime.h>

typedef unsigned short u16;
typedef __attribute__((ext_vector_type(8))) short s8v;   // 8 x bf16 (4 VGPRs)
typedef __attribute__((ext_vector_type(4))) float f4v;   // MFMA acc

#define MFMA16(a, b, c) __builtin_amdgcn_mfma_f32_16x16x32_bf16(a, b, c, 0, 0, 0)

#define B_    2
#define L_    2048
#define D_    2048
#define H_    16
#define KVH_  4
#define HD_   128
#define F_    5632
#define FC_   1408        // F chunk (4 chunks)
#define MTOK  (B_ * L_)   // 4096
#define NEG_BIG (-1e30f)
#define SCL2E 0.127517416f   // 128^-0.5 * log2(e)

__device__ __forceinline__ float b2f(u16 h) {
  union { float f; unsigned u; } v; v.u = ((unsigned)h) << 16; return v.f;
}
__device__ __forceinline__ u16 f2b(float f) {
  union { float f; unsigned u; } v; v.f = f;
  unsigned r = v.u + 0x7FFFu + ((v.u >> 16) & 1u);
  return (u16)(r >> 16);
}
__device__ __forceinline__ s8v ld8(const u16* p) { return *reinterpret_cast<const s8v*>(p); }
__device__ __forceinline__ void st8(u16* p, s8v v) { *reinterpret_cast<s8v*>(p) = v; }
// async global->LDS, 16B per lane; lds dest = wave-uniform base + lane*16 [m97]
__device__ __forceinline__ void gld16(const u16* g, u16* l) {
  __builtin_amdgcn_global_load_lds((const __attribute__((address_space(1))) void*)g,
                                   (__attribute__((address_space(3))) void*)l, 16, 0, 0);
}

// ---------------- fp32 -> bf16 weight convert (grid-stride, 8/thread) -----
__global__ __launch_bounds__(256) void conv_k(const float* __restrict__ src,
                                              u16* __restrict__ dst, int n8) {
  int i = blockIdx.x * 256 + threadIdx.x;
  const int stride = gridDim.x * 256;
  for (; i < n8; i += stride) {
    const float* p = src + (size_t)i * 8;
    float4 a = *(const float4*)p, b = *(const float4*)(p + 4);
    float f[8] = {a.x, a.y, a.z, a.w, b.x, b.y, b.z, b.w};
    s8v o;
#pragma unroll
    for (int j = 0; j < 8; ++j) o[j] = (short)f2b(f[j]);
    st8(dst + (size_t)i * 8, o);
  }
}

// ---------------- concat q/k/v bias into [3072] ---------------------------
__global__ __launch_bounds__(256) void catbias_k(const float* __restrict__ qb,
                                                 const float* __restrict__ kb,
                                                 const float* __restrict__ vb,
                                                 float* __restrict__ o) {
  int i = blockIdx.x * 256 + threadIdx.x;
  float v;
  if (i < 2048) v = qb[i];
  else if (i < 2560) v = kb[i - 2048];
  else v = vb[i - 2560];
  o[i] = v;
}

// ---------------- silu(g) * u -> g, bf16, grid-stride 8/thread ------------
__global__ __launch_bounds__(256) void silumul_k(u16* __restrict__ g,
                                                 const u16* __restrict__ u, int n8) {
  int i = blockIdx.x * 256 + threadIdx.x;
  const int stride = gridDim.x * 256;
  for (; i < n8; i += stride) {
    s8v a = ld8(g + (size_t)i * 8);
    s8v b = ld8(u + (size_t)i * 8);
    s8v o;
#pragma unroll
    for (int j = 0; j < 8; ++j) {
      float gf = b2f((u16)a[j]);
      float uf = b2f((u16)b[j]);
      o[j] = (short)f2b(gf / (1.f + __expf(-gf)) * uf);
    }
    st8(g + (size_t)i * 8, o);
  }
}

// ---------------- RMSNorm: fp32 in -> bf16 out, one block per row ---------
__global__ __launch_bounds__(256) void rmsnorm_k(const float* __restrict__ x,
                                                 const float* __restrict__ w,
                                                 u16* __restrict__ out) {
  const int row = blockIdx.x, t = threadIdx.x;
  const float* xr = x + (size_t)row * D_ + t * 8;
  float4 a = *(const float4*)(xr);
  float4 b = *(const float4*)(xr + 4);
  float f[8] = {a.x, a.y, a.z, a.w, b.x, b.y, b.z, b.w};
  float ss = 0.f;
#pragma unroll
  for (int j = 0; j < 8; ++j) ss += f[j] * f[j];
#pragma unroll
  for (int m = 1; m < 64; m <<= 1) ss += __shfl_xor(ss, m);
  __shared__ float red[4];
  if ((t & 63) == 0) red[t >> 6] = ss;
  __syncthreads();
  float tot = red[0] + red[1] + red[2] + red[3];
  float inv = rsqrtf(tot * (1.f / D_) + 1e-6f);
  float4 wa = *(const float4*)(w + t * 8);
  float4 wb = *(const float4*)(w + t * 8 + 4);
  float wf[8] = {wa.x, wa.y, wa.z, wa.w, wb.x, wb.y, wb.z, wb.w};
  s8v o;
#pragma unroll
  for (int j = 0; j < 8; ++j) o[j] = (short)f2b(f[j] * inv * wf[j]);
  st8(out + (size_t)row * D_ + t * 8, o);
}

// ======== GEMM variant 1: A bf16, W bf16, global_load_lds staging =========
// C[4096, Ntiles*128] = A * W^T, 128x128 tile, single-barrier triple-buffered
// depth-2 prefetch (counted vmcnt), T1 XCD remap (n-outer/m-inner), chunk-XOR
// swizzled LDS (pre-swizzled global source, rule 21).
// Split mode (W2 != nullptr): n-tiles with n0 >= nsplit read W2 and write Cv2
// (both outputs row-stride ldc) -- used to fuse the gate & up projections
// into ONE dispatch for 2x blocks/CU.
template <bool C_F32>
__global__ __launch_bounds__(256) void gemm_bb(const u16* __restrict__ A, int lda,
                                               const u16* __restrict__ W,
                                               const u16* __restrict__ W2,
                                               int ldw, int nsplit,
                                               const float* __restrict__ bias,
                                               const float* resid,
                                               const u16* gatein,
                                               void* Cv, void* Cv2,
                                               int ldc, int K) {
  __shared__ __align__(16) u16 As[3][128 * 32];
  __shared__ __align__(16) u16 Bs[3][128 * 32];
  const int t = threadIdx.x;
  const int l = t & 63, w = t >> 6;
  const int lr = l & 15, lg = l >> 4;
  // T1: bijective XCD chunk remap; pos enumerated n-outer, m-inner (M/128=32)
  const int total = gridDim.x;
  const int qd = total >> 3, rr = total & 7;
  const int xc = blockIdx.x & 7, xi = blockIdx.x >> 3;
  const int pos = xc * qd + (xc < rr ? xc : rr) + xi;
  const int m0 = (pos & 31) * 128;
  int n0 = (pos >> 5) * 128;
  const u16* Wuse = W;
  void* Cuse = Cv;
  if (W2 && n0 >= nsplit) { Wuse = W2; Cuse = Cv2; n0 -= nsplit; }
  const int wm = (w >> 1) * 64, wn = (w & 1) * 64;
  // staging: thread t owns 16B chunk (row sr, phys chunk t&3); fetch the
  // LOGICAL chunk (t&3)^((sr>>1)&3) so physical layout is XOR-swizzled.
  const int sr = t >> 2;
  const int sc = (((t & 3) ^ ((t >> 3) & 3)) * 8);
  const u16* Ag0 = A + (size_t)(m0 + sr) * lda + sc;
  const u16* Ag1 = A + (size_t)(m0 + sr + 64) * lda + sc;
  const u16* Wg0 = Wuse + (size_t)(n0 + sr) * ldw + sc;
  const u16* Wg1 = Wuse + (size_t)(n0 + sr + 64) * ldw + sc;

  auto stage = [&](int buf, int koff) {
    gld16(Ag0 + koff, &As[buf][w * 512]);
    gld16(Ag1 + koff, &As[buf][2048 + w * 512]);
    gld16(Wg0 + koff, &Bs[buf][w * 512]);
    gld16(Wg1 + koff, &Bs[buf][2048 + w * 512]);
  };

  const f4v zero4 = {0.f, 0.f, 0.f, 0.f};
  f4v acc[4][4];
#pragma unroll
  for (int i = 0; i < 4; ++i)
#pragma unroll
    for (int j = 0; j < 4; ++j) acc[i][j] = zero4;

  // read-side chunk XOR: (row>>1)&3 == (lr>>1)&3 for all frag rows here
  const int xq = (lr >> 1) & 3;
  const int cofA = (lg ^ xq) * 8;

  stage(0, 0);
  if (K > 32) stage(1, 32);
  int cur = 0;
  for (int k0 = 0; k0 < K; k0 += 32) {
    // own tile-k loads done; up to 4 younger prefetch loads stay in flight
    if (k0 + 32 < K) asm volatile("s_waitcnt vmcnt(4)" ::: "memory");
    else             asm volatile("s_waitcnt vmcnt(0)" ::: "memory");
    __builtin_amdgcn_s_barrier();          // all waves' tile-k DMA landed;
                                           // also: all step k-1 reads done
    if (k0 + 64 < K) {                     // stage tile k+2 into buf read @k-1
      int nb = cur + 2; if (nb >= 3) nb -= 3;
      stage(nb, k0 + 64);
    }
    s8v af[4], bf[4];
#pragma unroll
    for (int i = 0; i < 4; ++i) {
      af[i] = ld8(&As[cur][(wm + i * 16 + lr) * 32 + cofA]);
      bf[i] = ld8(&Bs[cur][(wn + i * 16 + lr) * 32 + cofA]);
    }
    __builtin_amdgcn_s_setprio(1);
#pragma unroll
    for (int i = 0; i < 4; ++i)
#pragma unroll
      for (int j = 0; j < 4; ++j)
        acc[i][j] = MFMA16(af[i], bf[j], acc[i][j]);
    __builtin_amdgcn_s_setprio(0);
    ++cur; if (cur == 3) cur = 0;
  }
  // epilogue: C/D layout col = lane&15, row = (lane>>4)*4 + reg  [m89]
#pragma unroll
  for (int j = 0; j < 4; ++j) {
    const int col = n0 + wn + j * 16 + lr;
    const float bv = bias ? bias[col] : 0.f;
#pragma unroll
    for (int i = 0; i < 4; ++i) {
      const int row = m0 + wm + i * 16 + lg * 4;
#pragma unroll
      for (int r = 0; r < 4; ++r) {
        float vv = acc[i][j][r] + bv;
        size_t off = (size_t)(row + r) * ldc + col;
        if (gatein) {
          float gf = b2f(gatein[off]);
          vv *= gf / (1.f + __expf(-gf));   // silu(gate) * up
        }
        if (resid) vv += resid[off];
        if (C_F32) ((float*)Cuse)[off] = vv;
        else       ((u16*)Cuse)[off]   = f2b(vv);
      }
    }
  }
}

// ======== GEMM variant 2 (fallback): A bf16, W fp32 staged in regs ========
template <bool C_F32>
__global__ __launch_bounds__(256) void gemm_nt(const u16* __restrict__ A, int lda,
                                               const float* __restrict__ W, int ldw,
                                               const float* __restrict__ bias,
                                               const float* resid,
                                               const u16* gatein,
                                               void* Cv,
                                               int M, int N, int K) {
  __shared__ __align__(16) u16 As[128 * 32];
  __shared__ __align__(16) u16 Bs[128 * 32];
  const int t = threadIdx.x;
  const int l = t & 63, w = t >> 6;
  const int lr = l & 15, lg = l >> 4;
  const int m0 = blockIdx.y * 128, n0 = blockIdx.x * 128;
  const int wm = (w >> 1) * 64, wn = (w & 1) * 64;
  const int sr = t >> 2, sc = (t & 3) * 8;
  const u16* Ag0 = A + (size_t)(m0 + sr) * lda + sc;
  const u16* Ag1 = A + (size_t)(m0 + sr + 64) * lda + sc;
  const float* Wg0 = W + (size_t)(n0 + sr) * ldw + sc;
  const float* Wg1 = W + (size_t)(n0 + sr + 64) * ldw + sc;

  const f4v zero4 = {0.f, 0.f, 0.f, 0.f};
  f4v acc[4][4];
#pragma unroll
  for (int i = 0; i < 4; ++i)
#pragma unroll
    for (int j = 0; j < 4; ++j) acc[i][j] = zero4;

  for (int k0 = 0; k0 < K; k0 += 32) {
    s8v a0 = ld8(Ag0 + k0), a1 = ld8(Ag1 + k0);
    float4 w0a = *(const float4*)(Wg0 + k0), w0b = *(const float4*)(Wg0 + k0 + 4);
    float4 w1a = *(const float4*)(Wg1 + k0), w1b = *(const float4*)(Wg1 + k0 + 4);
    float wf0[8] = {w0a.x, w0a.y, w0a.z, w0a.w, w0b.x, w0b.y, w0b.z, w0b.w};
    float wf1[8] = {w1a.x, w1a.y, w1a.z, w1a.w, w1b.x, w1b.y, w1b.z, w1b.w};
    s8v b0, b1;
#pragma unroll
    for (int j = 0; j < 8; ++j) { b0[j] = (short)f2b(wf0[j]); b1[j] = (short)f2b(wf1[j]); }
    __syncthreads();
    st8(&As[sr * 32 + sc], a0);
    st8(&As[(sr + 64) * 32 + sc], a1);
    st8(&Bs[sr * 32 + sc], b0);
    st8(&Bs[(sr + 64) * 32 + sc], b1);
    __syncthreads();
    s8v af[4], bf[4];
#pragma unroll
    for (int i = 0; i < 4; ++i) {
      af[i] = ld8(&As[(wm + i * 16 + lr) * 32 + lg * 8]);
      bf[i] = ld8(&Bs[(wn + i * 16 + lr) * 32 + lg * 8]);
    }
#pragma unroll
    for (int i = 0; i < 4; ++i)
#pragma unroll
      for (int j = 0; j < 4; ++j)
        acc[i][j] = MFMA16(af[i], bf[j], acc[i][j]);
  }
#pragma unroll
  for (int j = 0; j < 4; ++j) {
    const int col = n0 + wn + j * 16 + lr;
    const float bv = bias ? bias[col] : 0.f;
#pragma unroll
    for (int i = 0; i < 4; ++i) {
      const int row = m0 + wm + i * 16 + lg * 4;
#pragma unroll
      for (int r = 0; r < 4; ++r) {
        float vv = acc[i][j][r] + bv;
        size_t off = (size_t)(row + r) * N + col;
        if (gatein) {
          float gf = b2f(gatein[off]);
          vv *= gf / (1.f + __expf(-gf));
        }
        if (resid) vv += resid[off];
        if (C_F32) ((float*)Cv)[off] = vv;
        else       ((u16*)Cv)[off]   = f2b(vv);
      }
    }
  }
}

// ---------------- V transpose: bf16 [B,L,ldv] -> VT [B][KVH][HD][L] -------
__global__ __launch_bounds__(256) void transpose_v(const u16* __restrict__ V, int ldv,
                                                   u16* __restrict__ VT) {
  __shared__ u16 tile[64][72];
  const int t = threadIdx.x;
  const int tok0 = blockIdx.x * 64;
  const int hd0 = blockIdx.y * 64;
  const int bk = blockIdx.z;           // b*KVH + kvh
  const int b = bk >> 2, kvh = bk & 3;
#pragma unroll
  for (int c = 0; c < 16; ++c) {
    int idx = t + c * 256;
    int tok = idx >> 6, hd = idx & 63;
    tile[tok][hd] = V[(size_t)(b * L_ + tok0 + tok) * ldv + kvh * 128 + hd0 + hd];
  }
  __syncthreads();
#pragma unroll
  for (int c = 0; c < 16; ++c) {
    int idx = t + c * 256;
    int tok = idx & 63, hd = idx >> 6;
    VT[(size_t)(bk * 128 + hd0 + hd) * L_ + tok0 + tok] = tile[tok][hd];
  }
}

// ---------------- Flash attention, causal, GQA (kv = h % 4), all bf16 -----
// q-tile 64, 4 waves (wave w owns q rows w*16..+15), k-tiles of 64 keys.
// double-buffered global_load_lds staging (2-phase pipeline, T3/T14),
// XOR-swizzled K/V tiles (linear dest + pre-swizzled source, rule 21),
// reversed q-tile launch order (long causal blocks first), setprio (T5).
// Q/K read from strided buffers (qkv fused layout).
__global__ __launch_bounds__(256) void attn_k(const u16* __restrict__ Q, int ldq,
                                              const u16* __restrict__ Kx, int ldk,
                                              const u16* __restrict__ VT,
                                              u16* __restrict__ O) {
  __shared__ __align__(16) u16 KtB[2][64 * 128];   // [key][hd], swizzled
  __shared__ __align__(16) u16 VtB[2][128 * 64];   // [hd][key], swizzled
  __shared__ __align__(16) u16 Pb[4 * 16 * 72];    // per-wave [qlocal][key]
  const int t = threadIdx.x, l = t & 63, w = t >> 6;
  const int lr = l & 15, lg = l >> 4;
  const int bh = blockIdx.y, b = bh >> 4, h = bh & 15, kvh = h & 3;
  const int qt = (int)gridDim.x - 1 - blockIdx.x;  // heavy blocks dispatch first
  const int q0 = qt * 64;
  const int ktmax = qt;
  const f4v zero4 = {0.f, 0.f, 0.f, 0.f};

  // staging geometry: linear LDS dest (idx = c*256+t, 16B chunks);
  // source column pre-XOR'd so a swizzled read is conflict-free.
  const int kxr = t >> 4;                     // K: row-in-group 0..15
  const int kxc = (t & 15) ^ (kxr & 7);       // K: swizzled 16B chunk 0..15
  const int vxr = t >> 3;                     // V: row-in-group 0..31
  const int vxc = (t & 7) ^ (vxr & 7);        // V: swizzled 16B chunk 0..7
  const u16* Kg = Kx + (size_t)(b * L_) * ldk + kvh * 128;
  const u16* Vg = VT + (size_t)((b * 4 + kvh) * 128) * L_;

  auto stage = [&](int ktile, int bufi) {
#pragma unroll
    for (int c = 0; c < 4; ++c)
      gld16(Kg + (size_t)(ktile * 64 + c * 16 + kxr) * ldk + kxc * 8,
            &KtB[bufi][c * 2048 + w * 512]);
#pragma unroll
    for (int c = 0; c < 4; ++c)
      gld16(Vg + (size_t)(c * 32 + vxr) * L_ + ktile * 64 + vxc * 8,
            &VtB[bufi][c * 2048 + w * 512]);
  };

  // Q fragments (A-layout: m = lane&15, k = (lane>>4)*8+j)
  s8v qf[4];
#pragma unroll
  for (int kf = 0; kf < 4; ++kf)
    qf[kf] = ld8(Q + (size_t)(b * L_ + q0 + w * 16 + lr) * ldq +
                 h * 128 + kf * 32 + lg * 8);

  float mrow[4], srow[4];
  f4v oacc[8];
#pragma unroll
  for (int r = 0; r < 4; ++r) { mrow[r] = NEG_BIG; srow[r] = 0.f; }
#pragma unroll
  for (int n = 0; n < 8; ++n) oacc[n] = zero4;
  u16* Pw = Pb + w * 16 * 72;

  int cur = 0;
  stage(0, 0);
  asm volatile("s_waitcnt vmcnt(0)" ::: "memory");
  __syncthreads();

  for (int kt = 0; kt <= ktmax; ++kt) {
    if (kt < ktmax) stage(kt + 1, cur ^ 1);   // async prefetch next tile

    // S = Q K^T  (1 mf x 4 nf, K=128 via 4 kf)
    f4v s[4];
#pragma unroll
    for (int nf = 0; nf < 4; ++nf) s[nf] = zero4;
    __builtin_amdgcn_s_setprio(1);
#pragma unroll
    for (int nf = 0; nf < 4; ++nf)
#pragma unroll
      for (int kf = 0; kf < 4; ++kf) {
        s8v bfr = ld8(&KtB[cur][(nf * 16 + lr) * 128 +
                                ((kf * 4 + lg) ^ (lr & 7)) * 8]);
        s[nf] = MFMA16(qf[kf], bfr, s[nf]);
      }
    __builtin_amdgcn_s_setprio(0);

    const bool needmask = (kt == ktmax);
#pragma unroll
    for (int nf = 0; nf < 4; ++nf)
#pragma unroll
      for (int r = 0; r < 4; ++r) {
        float vv = s[nf][r] * SCL2E;
        if (needmask) {
          int key = kt * 64 + nf * 16 + lr;
          int qr = q0 + w * 16 + lg * 4 + r;
          if (key > qr) vv = NEG_BIG;
        }
        s[nf][r] = vv;
      }

    // row max (16 lr-lanes x 4 nf)
    float tm[4];
#pragma unroll
    for (int r = 0; r < 4; ++r) {
      float m = fmaxf(fmaxf(s[0][r], s[1][r]), fmaxf(s[2][r], s[3][r]));
#pragma unroll
      for (int msk = 1; msk < 16; msk <<= 1) m = fmaxf(m, __shfl_xor(m, msk));
      tm[r] = m;
    }
    float al[4], rs[4];
#pragma unroll
    for (int r = 0; r < 4; ++r) {
      float mn = fmaxf(mrow[r], tm[r]);
      al[r] = exp2f(mrow[r] - mn);
      mrow[r] = mn;
      rs[r] = 0.f;
    }
    // P = exp2(S - m); bf16 P to per-wave LDS (wave-private, in-order DS)
#pragma unroll
    for (int nf = 0; nf < 4; ++nf)
#pragma unroll
      for (int r = 0; r < 4; ++r) {
        float p = exp2f(s[nf][r] - mrow[r]);
        rs[r] += p;
        Pw[(lg * 4 + r) * 72 + nf * 16 + lr] = f2b(p);
      }
#pragma unroll
    for (int r = 0; r < 4; ++r) {
#pragma unroll
      for (int msk = 1; msk < 16; msk <<= 1) rs[r] += __shfl_xor(rs[r], msk);
      srow[r] = srow[r] * al[r] + rs[r];
    }
#pragma unroll
    for (int n = 0; n < 8; ++n)
#pragma unroll
      for (int r = 0; r < 4; ++r) oacc[n][r] *= al[r];

    // O += P V
    s8v pa[2];
#pragma unroll
    for (int k2 = 0; k2 < 2; ++k2)
      pa[k2] = ld8(&Pw[lr * 72 + k2 * 32 + lg * 8]);
    __builtin_amdgcn_s_setprio(1);
#pragma unroll
    for (int n = 0; n < 8; ++n)
#pragma unroll
      for (int k2 = 0; k2 < 2; ++k2) {
        s8v vb = ld8(&VtB[cur][(n * 16 + lr) * 64 +
                               ((k2 * 4 + lg) ^ (lr & 7)) * 8]);
        oacc[n] = MFMA16(pa[k2], vb, oacc[n]);
      }
    __builtin_amdgcn_s_setprio(0);

    asm volatile("s_waitcnt vmcnt(0)" ::: "memory");  // prefetch landed
    __syncthreads();                                   // all waves done w/ cur
    cur ^= 1;
  }

  // normalize + store (bf16)
#pragma unroll
  for (int r = 0; r < 4; ++r) {
    float inv = 1.f / srow[r];
#pragma unroll
    for (int n = 0; n < 8; ++n) {
      size_t off = (size_t)(b * L_ + q0 + w * 16 + lg * 4 + r) * 2048 +
                   h * 128 + n * 16 + lr;
      O[off] = f2b(oacc[n][r] * inv);
    }
  }
}

// ---------------- launch ---------------------------------------------------
extern "C" void kernel_launch(void* const* d_in, const int* in_sizes, int n_in,
                              void* d_out, int out_size, void* d_ws, size_t ws_size,
                              hipStream_t stream) {
  const float* x    = (const float*)d_in[0];
  const float* ln1w = (const float*)d_in[1];
  const float* qw   = (const float*)d_in[2];
  const float* qb   = (const float*)d_in[3];
  const float* kw   = (const float*)d_in[4];
  const float* kb   = (const float*)d_in[5];
  const float* vw   = (const float*)d_in[6];
  const float* vbi  = (const float*)d_in[7];
  const float* ow   = (const float*)d_in[8];
  const float* ln2w = (const float*)d_in[9];
  const float* gw   = (const float*)d_in[10];
  const float* uw   = (const float*)d_in[11];
  const float* dw   = (const float*)d_in[12];
  float* out = (float*)d_out;

  char* ws = (char*)d_ws;
  u16* h    = (u16*)(ws);                  // 16 MiB
  u16* kbuf = (u16*)(ws + (16ull << 20));  // 4 MiB (fallback only)
  u16* vbuf = (u16*)(ws + (20ull << 20));  // 4 MiB (fallback only)
  u16* vt   = (u16*)(ws + (24ull << 20));  // 4 MiB
  u16* g    = (u16*)(ws + (16ull << 20));  // 11 MiB (MLP phase; vt dead then)
  u16* qscr = (u16*)d_out;                 // bf16 scratch in d_out

  dim3 blk(256);
  const bool big = ws_size >= 119537664ull;   // bf16-weight path needs ~114 MiB

  rmsnorm_k<<<MTOK, blk, 0, stream>>>(x, ln1w, h);

  if (big) {
    // bf16 weight pool at +28 MiB  (wq|wk|wv contiguous -> fused QKV weight)
    u16* wp = (u16*)(ws + (28ull << 20));
    u16* wq = wp;                          // 4,194,304 elems (2048 rows)
    u16* wk = wq + 4194304;                // 1,048,576     (512 rows)
    u16* wv = wk + 1048576;                // 1,048,576     (512 rows)
    u16* wo = wv + 1048576;                // 4,194,304
    u16* wg = wo + 4194304;                // 11,534,336
    u16* wu = wg + 11534336;               // 11,534,336
    u16* wd = wu + 11534336;               // 11,534,336
    conv_k<<<2048, blk, 0, stream>>>(qw, wq, 4194304 / 8);
    conv_k<<<512, blk, 0, stream>>>(kw, wk, 1048576 / 8);
    conv_k<<<512, blk, 0, stream>>>(vw, wv, 1048576 / 8);
    conv_k<<<2048, blk, 0, stream>>>(ow, wo, 4194304 / 8);
    conv_k<<<2048, blk, 0, stream>>>(gw, wg, 11534336 / 8);
    conv_k<<<2048, blk, 0, stream>>>(uw, wu, 11534336 / 8);
    conv_k<<<2048, blk, 0, stream>>>(dw, wd, 11534336 / 8);

    float* biasc = (float*)(ws + (16ull << 20));   // [3072] f32 (kbuf region)
    catbias_k<<<12, blk, 0, stream>>>(qb, kb, vbi, biasc);

    // fused QKV projection: C = [4096][3072] bf16 in d_out
    u16* qkv = (u16*)d_out;
    gemm_bb<false><<<768, blk, 0, stream>>>(h, D_, wq, nullptr, D_, 1 << 30,
                                            biasc, nullptr, nullptr,
                                            qkv, nullptr, 3072, D_);
    transpose_v<<<dim3(32, 2, 8), blk, 0, stream>>>(qkv + 2560, 3072, vt);
    attn_k<<<dim3(32, 32), blk, 0, stream>>>(qkv, 3072, qkv + 2048, 3072, vt, h);
    gemm_bb<true><<<512, blk, 0, stream>>>(h, D_, wo, nullptr, D_, 1 << 30,
                                           nullptr, x, nullptr,
                                           d_out, nullptr, 2048, D_);
    rmsnorm_k<<<MTOK, blk, 0, stream>>>(out, ln2w, h);
    // MLP: per chunk, ONE fused gate+up dispatch (704 blocks = 2.75/CU) into
    // raw g (gate) and u (up); u reuses the dead wq/wk/wv region (12 MiB).
    u16* u = wq;
    for (int fc = 0; fc < 4; ++fc) {
      const u16* gwc = wg + (size_t)fc * FC_ * D_;
      const u16* uwc = wu + (size_t)fc * FC_ * D_;
      const u16* dwc = wd + (size_t)fc * FC_;
      gemm_bb<false><<<704, blk, 0, stream>>>(h, D_, gwc, uwc, D_, FC_,
                                              nullptr, nullptr, nullptr,
                                              g, u, FC_, D_);
      silumul_k<<<2048, blk, 0, stream>>>(g, u, MTOK * FC_ / 8);
      gemm_bb<true><<<512, blk, 0, stream>>>(g, FC_, dwc, nullptr, F_, 1 << 30,
                                             nullptr, out, nullptr,
                                             d_out, nullptr, 2048, FC_);
    }
  } else {
    // fallback: fp32-weight register staging (round-4 proven path, 27 MiB)
    gemm_nt<false><<<dim3(16, 32), blk, 0, stream>>>(h, D_, qw, D_, qb, nullptr, nullptr,
                                                     qscr, MTOK, 2048, 2048);
    gemm_nt<false><<<dim3(4, 32), blk, 0, stream>>>(h, D_, kw, D_, kb, nullptr, nullptr,
                                                    kbuf, MTOK, 512, 2048);
    gemm_nt<false><<<dim3(4, 32), blk, 0, stream>>>(h, D_, vw, D_, vbi, nullptr, nullptr,
                                                    vbuf, MTOK, 512, 2048);
    transpose_v<<<dim3(32, 2, 8), blk, 0, stream>>>(vbuf, 512, vt);
    attn_k<<<dim3(32, 32), blk, 0, stream>>>(qscr, 2048, kbuf, 512, vt, h);
    gemm_nt<true><<<dim3(16, 32), blk, 0, stream>>>(h, D_, ow, D_, nullptr, x, nullptr,
                                                    d_out, MTOK, 2048, 2048);
    rmsnorm_k<<<MTOK, blk, 0, stream>>>(out, ln2w, h);
    for (int fc = 0; fc < 4; ++fc) {
      const float* gwc = gw + (size_t)fc * FC_ * D_;
      const float* uwc = uw + (size_t)fc * FC_ * D_;
      const float* dwc = dw + (size_t)fc * FC_;
      gemm_nt<false><<<dim3(11, 32), blk, 0, stream>>>(h, D_, gwc, D_, nullptr, nullptr,
                                                       nullptr, g, MTOK, FC_, 2048);
      gemm_nt<false><<<dim3(11, 32), blk, 0, stream>>>(h, D_, uwc, D_, nullptr, nullptr,
                                                       g, g, MTOK, FC_, 2048);
      gemm_nt<true><<<dim3(16, 32), blk, 0, stream>>>(g, FC_, dwc, F_, nullptr, out,
                                                      nullptr, d_out, MTOK, 2048, FC_);
    }
  }
}